// Round 7
// baseline (215.026 us; speedup 1.0000x reference)
//
#include <hip/hip_runtime.h>
#include <math.h>

#define NRAYS 2048
#define TOT   128
#define INDS  16
#define HID   64
#define EPSF  1e-8f
#define MTOT  (NRAYS*TOT)

typedef float f32x2 __attribute__((ext_vector_type(2)));
typedef float f32x4 __attribute__((ext_vector_type(4)));

__device__ __forceinline__ float softplus_f(float x) {
    return fmaxf(x, 0.0f) + __logf(1.0f + __expf(-fabsf(x)));
}
__device__ __forceinline__ float sigmoid_f(float x) {
    return 1.0f / (1.0f + __expf(-x));
}
__device__ __forceinline__ float tanh_fast(float x) {
    float e2 = __expf(2.0f * x);
    return 1.0f - 2.0f / (e2 + 1.0f);
}
__device__ __forceinline__ f32x2 pkmax(f32x2 a, f32x2 b) {
    f32x2 r; r.x = fmaxf(a.x, b.x); r.y = fmaxf(a.y, b.y); return r;
}

// Build the 8 jittered z samples for this half (kbase = 0 or 8).
#define MAKE_Z(jp, kbase, nears, span)                                        \
    const float4* jp4 = (const float4*)(jp);                                  \
    float4 jA = jp4[0], jB = jp4[1];                                          \
    float s16 = (span) * (1.0f/16.0f);                                        \
    float hs16 = 0.5f * s16;                                                  \
    f32x2 z01, z23, z45, z67;                                                 \
    z01.x = fmaf(jA.x, s16, fmaf((float)((kbase)+0)*(1.0f/15.0f), span, nears) - hs16); \
    z01.y = fmaf(jA.y, s16, fmaf((float)((kbase)+1)*(1.0f/15.0f), span, nears) - hs16); \
    z23.x = fmaf(jA.z, s16, fmaf((float)((kbase)+2)*(1.0f/15.0f), span, nears) - hs16); \
    z23.y = fmaf(jA.w, s16, fmaf((float)((kbase)+3)*(1.0f/15.0f), span, nears) - hs16); \
    z45.x = fmaf(jB.x, s16, fmaf((float)((kbase)+4)*(1.0f/15.0f), span, nears) - hs16); \
    z45.y = fmaf(jB.y, s16, fmaf((float)((kbase)+5)*(1.0f/15.0f), span, nears) - hs16); \
    z67.x = fmaf(jB.z, s16, fmaf((float)((kbase)+6)*(1.0f/15.0f), span, nears) - hs16); \
    z67.y = fmaf(jB.w, s16, fmaf((float)((kbase)+7)*(1.0f/15.0f), span, nears) - hs16);

// Inner body given packed A2,B2 and packed weight pairs W0,W1,W2v.
#define DENSITY_J_BODY(A2, B2, W0, W1, W2v)                                   \
    {                                                                         \
        f32x2 g01 = z01*(B2) + (A2);                                          \
        f32x2 g23 = z23*(B2) + (A2);                                          \
        f32x2 g45 = z45*(B2) + (A2);                                          \
        f32x2 g67 = z67*(B2) + (A2);                                          \
        f32x2 h01, h23, h45, h67;                                             \
        h01.x = __builtin_amdgcn_sinf(g01.x); h01.y = __builtin_amdgcn_sinf(g01.y); \
        h23.x = __builtin_amdgcn_sinf(g23.x); h23.y = __builtin_amdgcn_sinf(g23.y); \
        h45.x = __builtin_amdgcn_sinf(g45.x); h45.y = __builtin_amdgcn_sinf(g45.y); \
        h67.x = __builtin_amdgcn_sinf(g67.x); h67.y = __builtin_amdgcn_sinf(g67.y); \
        a0_01 += h01*(W0); a0_23 += h23*(W0); a0_45 += h45*(W0); a0_67 += h67*(W0); \
        a1_01 += h01*(W1); a1_23 += h23*(W1); a1_45 += h45*(W1); a1_67 += h67*(W1); \
        a2_01 += h01*(W2v); a2_23 += h23*(W2v); a2_45 += h45*(W2v); a2_67 += h67*(W2v); \
    }

#define DENSITY_EPILOG(mx0o, mx1o, mx2o)                                      \
    {                                                                         \
        f32x2 p0 = pkmax(pkmax(a0_01, a0_23), pkmax(a0_45, a0_67));           \
        f32x2 p1 = pkmax(pkmax(a1_01, a1_23), pkmax(a1_45, a1_67));           \
        f32x2 p2 = pkmax(pkmax(a2_01, a2_23), pkmax(a2_45, a2_67));           \
        mx0o = fmaxf(p0.x, p0.y);                                             \
        mx1o = fmaxf(p1.x, p1.y);                                             \
        mx2o = fmaxf(p2.x, p2.y);                                             \
    }

#define DECL_ACC                                                              \
    f32x2 a0_01 = {0.f,0.f}, a0_23 = {0.f,0.f}, a0_45 = {0.f,0.f}, a0_67 = {0.f,0.f}; \
    f32x2 a1_01 = {0.f,0.f}, a1_23 = {0.f,0.f}, a1_45 = {0.f,0.f}, a1_67 = {0.f,0.f}; \
    f32x2 a2_01 = {0.f,0.f}, a2_23 = {0.f,0.f}, a2_45 = {0.f,0.f}, a2_67 = {0.f,0.f};

// LDS layout: operands stored PRE-DUPLICATED so packed FMAs consume ds_read
// results directly (zero v_mov broadcasts in the depth-0 loop).
// Hot loops are DS-only (in-order lgkmcnt pipelining — r4 showed SMEM+DS
// mixing forces per-iter drains). unroll 2: ds-prefetch in flight ~16 regs,
// total live set allocated at 40 VGPRs in r6 -> fits the (256,8) 64-budget.

// Depth-0: A,B block-uniform, fully packed from LDS.
__device__ __forceinline__ void density_max3_half_d0(
    const f32x4* __restrict__ sAB, const f32x4* __restrict__ sW01,
    const f32x2* __restrict__ sW2,
    float nears, float span, const float* __restrict__ jp, int kbase,
    float& mx0o, float& mx1o, float& mx2o)
{
    MAKE_Z(jp, kbase, nears, span)
    DECL_ACC
    #pragma unroll 2
    for (int j = 0; j < HID; ++j) {
        f32x4 ab  = sAB[j];    // {A,A,B,B}
        f32x4 w01 = sW01[j];   // {w20,w20,w21,w21}
        f32x2 w2  = sW2[j];    // {w22,w22}
        f32x2 A2 = {ab.x, ab.y}, B2 = {ab.z, ab.w};
        f32x2 W0 = {w01.x, w01.y}, W1 = {w01.z, w01.w};
        DENSITY_J_BODY(A2, B2, W0, W1, w2)
    }
    DENSITY_EPILOG(mx0o, mx1o, mx2o)
}

// Depth-1: o,d diverge -> A,B from pre-scaled w1 (6 fma) then broadcast.
__device__ __forceinline__ void density_max3_half_d1(
    const f32x4* __restrict__ sPW, const f32x4* __restrict__ sW01,
    const f32x2* __restrict__ sW2,
    float ox, float oy, float oz, float dx, float dy, float dz,
    float nears, float span, const float* __restrict__ jp, int kbase,
    float& mx0o, float& mx1o, float& mx2o)
{
    MAKE_Z(jp, kbase, nears, span)
    DECL_ACC
    #pragma unroll 2
    for (int j = 0; j < HID; ++j) {
        f32x4 pw  = sPW[j];    // {pw1x,pw1y,pw1z,-}
        f32x4 w01 = sW01[j];
        f32x2 w2  = sW2[j];
        float A = ox*pw.x + oy*pw.y + oz*pw.z;
        float B = dx*pw.x + dy*pw.y + dz*pw.z;
        f32x2 A2 = {A, A}, B2 = {B, B};
        f32x2 W0 = {w01.x, w01.y}, W1 = {w01.z, w01.w};
        DENSITY_J_BODY(A2, B2, W0, W1, w2)
    }
    DENSITY_EPILOG(mx0o, mx1o, mx2o)
}

__device__ __forceinline__ void env_logv(
    const float* __restrict__ env_map,
    float px, float py, float pz,
    float& v0, float& v1, float& v2)
{
    float theta = atan2f(px, -pz) * (1.0f/3.14159265358979323846f);
    float acv = (fabsf(py) <= 1.0f) ? acosf(py) : 0.0f;  // nan_to_num(arccos)
    float phi = 0.63661977236758134308f * acv - 1.0f;    // 2/pi
    float ixf = ((theta + 1.0f)*256.0f - 1.0f)*0.5f;
    float iyf = ((phi   + 1.0f)*128.0f - 1.0f)*0.5f;
    float x0f = floorf(ixf), y0f = floorf(iyf);
    float wx = ixf - x0f, wy = iyf - y0f;
    v0 = 0.f; v1 = 0.f; v2 = 0.f;
    auto tap = [&](float xc, float yc, float w) {
        if (xc >= 0.0f && xc < 256.0f && yc >= 0.0f && yc < 128.0f) {
            int xi = (int)xc, yi = (int)yc;
            const float* e = env_map + yi*256 + xi;
            v0 += w * e[0];
            v1 += w * e[128*256];
            v2 += w * e[2*128*256];
        }
    };
    tap(x0f,      y0f,      (1.0f-wx)*(1.0f-wy));
    tap(x0f+1.0f, y0f,      wx*(1.0f-wy));
    tap(x0f,      y0f+1.0f, (1.0f-wx)*wy);
    tap(x0f+1.0f, y0f+1.0f, wx*wy);
}

// 256 threads/block = 1 ray; lane pair (2s,2s+1) shares sub-ray s.
// (256,8): work = 8 blocks/CU, resident = 8 -> ONE full pass, no tail.
// r6's (256,6) left a 2-block tail per CU (makespan 2T vs ideal 1.33T;
// OccupancyPercent 43% was the smoking gun). r6 measured the unroll-2
// live set at 40 VGPRs, so the 64-reg budget here should NOT collapse
// (r5's collapse was the unroll-4 prefetch set).
__global__ __launch_bounds__(256, 8)
void render_kernel(const float* __restrict__ rays_o,
                   const float* __restrict__ rays_d,
                   const float* __restrict__ env_map,
                   const float* __restrict__ Wd1,
                   const float* __restrict__ Wd2,
                   const float* __restrict__ Wf1,
                   const float* __restrict__ Ws,
                   const float* __restrict__ Wdir,
                   const float* __restrict__ Wrho,
                   const float* __restrict__ jitter,
                   const float* __restrict__ u_t,
                   const float* __restrict__ u_scatter,
                   const int*   __restrict__ channel,
                   float* __restrict__ out)
{
    const int ray  = blockIdx.x;
    const int tid  = threadIdx.x;
    const int s    = tid >> 1;
    const int half = tid & 1;
    const int m    = ray * TOT + s;
    const int kbase = half * 8;

    __shared__ f32x4 sAB[HID];     // {A,A,B,B}
    __shared__ f32x4 sW01[HID];    // {w20,w20,w21,w21}
    __shared__ f32x2 sW2[HID];     // {w22,w22}
    __shared__ f32x4 sPW[HID];     // {pw1x,pw1y,pw1z,0}
    __shared__ float sred[4][3];

    float ox = rays_o[ray*3+0], oy = rays_o[ray*3+1], oz = rays_o[ray*3+2];
    float dx = rays_d[ray*3+0], dy = rays_d[ray*3+1], dz = rays_d[ray*3+2];

    // ---- per-block tables (block-uniform depth-0 geometry) ----
    if (tid < HID) {
        const float INV2PI = 0.15915494309189535f;
        float w1x = Wd1[tid], w1y = Wd1[HID+tid], w1z = Wd1[2*HID+tid];
        float pw1x = w1x*INV2PI, pw1y = w1y*INV2PI, pw1z = w1z*INV2PI;
        float A = ox*pw1x + oy*pw1y + oz*pw1z;
        float B = dx*pw1x + dy*pw1y + dz*pw1z;
        float w20 = Wd2[3*tid], w21 = Wd2[3*tid+1], w22 = Wd2[3*tid+2];
        sAB[tid]  = (f32x4){A, A, B, B};
        sW01[tid] = (f32x4){w20, w20, w21, w21};
        sW2[tid]  = (f32x2){w22, w22};
        sPW[tid]  = (f32x4){pw1x, pw1y, pw1z, 0.0f};
    }
    __syncthreads();

    float thr0 = 1.f, thr1 = 1.f, thr2 = 1.f;
    float rgb0 = 0.f, rgb1 = 0.f, rgb2 = 0.f;
    bool alive;

    // ================= depth 0 =================
    {
        float a = dx*dx + dy*dy + dz*dz;
        float b = 2.0f*(dx*ox + dy*oy + dz*oz);
        float c = (ox*ox + oy*oy + oz*oz) - 1.0f;
        float delta = b*b - 4.0f*a*c;
        alive = (delta > 0.0f);
        if (alive) {
            float sq    = sqrtf(delta);
            float nears = fmaxf((-b - sq) / (2.0f*a), 0.001f);
            float fars  = fmaxf((-b + sq) / (2.0f*a), 0.001f);
            float span  = fars - nears;

            float mx0, mx1, mx2;
            density_max3_half_d0(sAB, sW01, sW2, nears, span,
                                 jitter + (size_t)m*INDS + kbase, kbase,
                                 mx0,mx1,mx2);
            mx0 = fmaxf(mx0, __shfl_xor(mx0, 1, 64));
            mx1 = fmaxf(mx1, __shfl_xor(mx1, 1, 64));
            mx2 = fmaxf(mx2, __shfl_xor(mx2, 1, 64));

            float maj0 = fmaxf(softplus_f(mx0), 0.001f);
            float maj1 = fmaxf(softplus_f(mx1), 0.001f);
            float maj2 = fmaxf(softplus_f(mx2), 0.001f);
            float mmax = fmaxf(fmaxf(maj0, maj1), maj2);

            int   ch  = channel[m];
            float maj = (ch == 0) ? maj0 : ((ch == 1) ? maj1 : maj2);
            float t   = -log1pf(-u_t[m]) / maj + nears;

            if (t >= fars) {
                float den0 = __expf(-maj0*span)/(mmax+EPSF) + EPSF;
                float den1 = __expf(-maj1*span)/(mmax+EPSF) + EPSF;
                float den2 = __expf(-maj2*span)/(mmax+EPSF) + EPSF;
                float idm = 3.0f / (den0+den1+den2);
                float v0,v1,v2;
                env_logv(env_map, fmaf(dx,fars,ox), fmaf(dy,fars,oy), fmaf(dz,fars,oz), v0,v1,v2);
                rgb0 = den0*idm*__expf(v0);
                rgb1 = den1*idm*__expf(v1);
                rgb2 = den2*idm*__expf(v2);
                alive = false;
            } else {
                float tn  = t - nears;
                float imm = 1.0f / mmax;
                float tr0 = __expf(-maj0*tn) * imm;
                float tr1 = __expf(-maj1*tn) * imm;
                float tr2 = __expf(-maj2*tn) * imm;
                float i2m = 3.0f / (maj0*tr0 + maj1*tr1 + maj2*tr2);
                thr0 = tr0 * i2m;   // thr was 1
                thr1 = tr1 * i2m;
                thr2 = tr2 * i2m;
                ox = fmaf(dx, t, ox); oy = fmaf(dy, t, oy); oz = fmaf(dz, t, oz);

                // material MLP, hidden dim split across the lane pair
                float st0=0.f, st1=0.f, st2=0.f;
                float dn0=0.f, dn1=0.f, dn2v=0.f;
                float rh0=0.f, rh1=0.f, rh2=0.f;
                const int j0 = half * 32;
                #pragma unroll 2
                for (int j = j0; j < j0 + 32; ++j) {
                    float pre = ox*Wf1[j] + oy*Wf1[HID+j] + oz*Wf1[2*HID+j]
                              + dx*Wf1[3*HID+j] + dy*Wf1[4*HID+j] + dz*Wf1[5*HID+j];
                    float f = tanh_fast(pre);
                    st0  = fmaf(f, Ws[j*3+0], st0);
                    st1  = fmaf(f, Ws[j*3+1], st1);
                    st2  = fmaf(f, Ws[j*3+2], st2);
                    dn0  = fmaf(f, Wdir[j*3+0], dn0);
                    dn1  = fmaf(f, Wdir[j*3+1], dn1);
                    dn2v = fmaf(f, Wdir[j*3+2], dn2v);
                    rh0  = fmaf(f, Wrho[j*3+0], rh0);
                    rh1  = fmaf(f, Wrho[j*3+1], rh1);
                    rh2  = fmaf(f, Wrho[j*3+2], rh2);
                }
                st0  += __shfl_xor(st0, 1, 64);
                st1  += __shfl_xor(st1, 1, 64);
                st2  += __shfl_xor(st2, 1, 64);
                dn0  += __shfl_xor(dn0, 1, 64);
                dn1  += __shfl_xor(dn1, 1, 64);
                dn2v += __shfl_xor(dn2v, 1, 64);
                rh0  += __shfl_xor(rh0, 1, 64);
                rh1  += __shfl_xor(rh1, 1, 64);
                rh2  += __shfl_xor(rh2, 1, 64);

                float stch = (ch == 0) ? st0 : ((ch == 1) ? st1 : st2);
                float sp = fminf(softplus_f(stch) / maj, 1.0f);
                if (u_scatter[m] < sp) {
                    float inr = 1.0f / (sqrtf(dn0*dn0 + dn1*dn1 + dn2v*dn2v) + EPSF);
                    dx = dn0*inr; dy = dn1*inr; dz = dn2v*inr;
                    float isp = 1.0f/(sp + EPSF);
                    thr0 *= isp * sigmoid_f(rh0);
                    thr1 *= isp * sigmoid_f(rh1);
                    thr2 *= isp * sigmoid_f(rh2);
                } else {
                    float iv = 1.0f/(1.0f - sp + EPSF);
                    thr0 *= iv; thr1 *= iv; thr2 *= iv;
                }
            }
        }
    }

    // ================= depth 1 (t = fars -> hit if delta>0) =================
    if (alive) {
        float a = dx*dx + dy*dy + dz*dz;
        float b = 2.0f*(dx*ox + dy*oy + dz*oz);
        float c = (ox*ox + oy*oy + oz*oz) - 1.0f;
        float delta = b*b - 4.0f*a*c;
        if (delta > 0.0f) {
            float sq    = sqrtf(delta);
            float nears = fmaxf((-b - sq) / (2.0f*a), 0.001f);
            float fars  = fmaxf((-b + sq) / (2.0f*a), 0.001f);
            float span  = fars - nears;

            float mx0, mx1, mx2;
            density_max3_half_d1(sPW, sW01, sW2, ox,oy,oz, dx,dy,dz, nears, span,
                                 jitter + ((size_t)MTOT + m)*INDS + kbase, kbase,
                                 mx0,mx1,mx2);
            mx0 = fmaxf(mx0, __shfl_xor(mx0, 1, 64));
            mx1 = fmaxf(mx1, __shfl_xor(mx1, 1, 64));
            mx2 = fmaxf(mx2, __shfl_xor(mx2, 1, 64));

            float maj0 = fmaxf(softplus_f(mx0), 0.001f);
            float maj1 = fmaxf(softplus_f(mx1), 0.001f);
            float maj2 = fmaxf(softplus_f(mx2), 0.001f);
            float mmax = fmaxf(fmaxf(maj0, maj1), maj2);

            float den0 = __expf(-maj0*span)/(mmax+EPSF) + EPSF;
            float den1 = __expf(-maj1*span)/(mmax+EPSF) + EPSF;
            float den2 = __expf(-maj2*span)/(mmax+EPSF) + EPSF;
            float idm = 3.0f / (den0+den1+den2);
            float v0,v1,v2;
            env_logv(env_map, fmaf(dx,fars,ox), fmaf(dy,fars,oy), fmaf(dz,fars,oz), v0,v1,v2);
            rgb0 += thr0 * den0*idm*__expf(v0);
            rgb1 += thr1 * den1*idm*__expf(v1);
            rgb2 += thr2 * den2*idm*__expf(v2);
        }
    }

    // ---- reduction: each sub-ray duplicated x2 -> sum/256 == mean/128 ----
    float r0 = rgb0, r1 = rgb1, r2 = rgb2;
    #pragma unroll
    for (int off = 32; off > 0; off >>= 1) {
        r0 += __shfl_down(r0, off, 64);
        r1 += __shfl_down(r1, off, 64);
        r2 += __shfl_down(r2, off, 64);
    }
    int wave = tid >> 6;
    if ((tid & 63) == 0) {
        sred[wave][0] = r0; sred[wave][1] = r1; sred[wave][2] = r2;
    }
    __syncthreads();
    if (tid == 0) {
        out[ray*3+0] = (sred[0][0]+sred[1][0]+sred[2][0]+sred[3][0]) * (1.0f/256.0f);
        out[ray*3+1] = (sred[0][1]+sred[1][1]+sred[2][1]+sred[3][1]) * (1.0f/256.0f);
        out[ray*3+2] = (sred[0][2]+sred[1][2]+sred[2][2]+sred[3][2]) * (1.0f/256.0f);
    }
}

extern "C" void kernel_launch(void* const* d_in, const int* in_sizes, int n_in,
                              void* d_out, int out_size, void* d_ws, size_t ws_size,
                              hipStream_t stream) {
    const float* rays_o    = (const float*)d_in[0];
    const float* rays_d    = (const float*)d_in[1];
    const float* env_map   = (const float*)d_in[2];
    const float* Wd1       = (const float*)d_in[3];
    const float* Wd2       = (const float*)d_in[4];
    const float* Wf1       = (const float*)d_in[5];
    const float* Ws        = (const float*)d_in[6];
    const float* Wdir      = (const float*)d_in[7];
    const float* Wrho      = (const float*)d_in[8];
    const float* jitter    = (const float*)d_in[9];
    const float* u_t       = (const float*)d_in[10];
    const float* u_scatter = (const float*)d_in[11];
    const int*   channel   = (const int*)d_in[12];
    float* out = (float*)d_out;

    render_kernel<<<dim3(NRAYS), dim3(256), 0, stream>>>(
        rays_o, rays_d, env_map, Wd1, Wd2, Wf1, Ws, Wdir, Wrho,
        jitter, u_t, u_scatter, channel, out);
}

// Round 8
// 213.938 us; speedup vs baseline: 1.0051x; 1.0051x over previous
//
#include <hip/hip_runtime.h>
#include <math.h>

#define NRAYS 2048
#define TOT   128
#define INDS  16
#define HID   64
#define EPSF  1e-8f
#define MTOT  (NRAYS*TOT)

typedef float f32x2 __attribute__((ext_vector_type(2)));
typedef float f32x4 __attribute__((ext_vector_type(4)));

__device__ __forceinline__ float softplus_f(float x) {
    return fmaxf(x, 0.0f) + __logf(1.0f + __expf(-fabsf(x)));
}
__device__ __forceinline__ float sigmoid_f(float x) {
    return 1.0f / (1.0f + __expf(-x));
}
__device__ __forceinline__ float tanh_fast(float x) {
    float e2 = __expf(2.0f * x);
    return 1.0f - 2.0f / (e2 + 1.0f);
}
__device__ __forceinline__ f32x2 pkmax(f32x2 a, f32x2 b) {
    f32x2 r; r.x = fmaxf(a.x, b.x); r.y = fmaxf(a.y, b.y); return r;
}

// Build the 8 jittered z samples for this half (kbase = 0 or 8).
#define MAKE_Z(jp, kbase, nears, span)                                        \
    const float4* jp4 = (const float4*)(jp);                                  \
    float4 jA = jp4[0], jB = jp4[1];                                          \
    float s16 = (span) * (1.0f/16.0f);                                        \
    float hs16 = 0.5f * s16;                                                  \
    f32x2 z01, z23, z45, z67;                                                 \
    z01.x = fmaf(jA.x, s16, fmaf((float)((kbase)+0)*(1.0f/15.0f), span, nears) - hs16); \
    z01.y = fmaf(jA.y, s16, fmaf((float)((kbase)+1)*(1.0f/15.0f), span, nears) - hs16); \
    z23.x = fmaf(jA.z, s16, fmaf((float)((kbase)+2)*(1.0f/15.0f), span, nears) - hs16); \
    z23.y = fmaf(jA.w, s16, fmaf((float)((kbase)+3)*(1.0f/15.0f), span, nears) - hs16); \
    z45.x = fmaf(jB.x, s16, fmaf((float)((kbase)+4)*(1.0f/15.0f), span, nears) - hs16); \
    z45.y = fmaf(jB.y, s16, fmaf((float)((kbase)+5)*(1.0f/15.0f), span, nears) - hs16); \
    z67.x = fmaf(jB.z, s16, fmaf((float)((kbase)+6)*(1.0f/15.0f), span, nears) - hs16); \
    z67.y = fmaf(jB.w, s16, fmaf((float)((kbase)+7)*(1.0f/15.0f), span, nears) - hs16);

// Inner body given packed A2,B2 and packed weight pairs W0,W1,W2v.
#define DENSITY_J_BODY(A2, B2, W0, W1, W2v)                                   \
    {                                                                         \
        f32x2 g01 = z01*(B2) + (A2);                                          \
        f32x2 g23 = z23*(B2) + (A2);                                          \
        f32x2 g45 = z45*(B2) + (A2);                                          \
        f32x2 g67 = z67*(B2) + (A2);                                          \
        f32x2 h01, h23, h45, h67;                                             \
        h01.x = __builtin_amdgcn_sinf(g01.x); h01.y = __builtin_amdgcn_sinf(g01.y); \
        h23.x = __builtin_amdgcn_sinf(g23.x); h23.y = __builtin_amdgcn_sinf(g23.y); \
        h45.x = __builtin_amdgcn_sinf(g45.x); h45.y = __builtin_amdgcn_sinf(g45.y); \
        h67.x = __builtin_amdgcn_sinf(g67.x); h67.y = __builtin_amdgcn_sinf(g67.y); \
        a0_01 += h01*(W0); a0_23 += h23*(W0); a0_45 += h45*(W0); a0_67 += h67*(W0); \
        a1_01 += h01*(W1); a1_23 += h23*(W1); a1_45 += h45*(W1); a1_67 += h67*(W1); \
        a2_01 += h01*(W2v); a2_23 += h23*(W2v); a2_45 += h45*(W2v); a2_67 += h67*(W2v); \
    }

#define DENSITY_EPILOG(mx0o, mx1o, mx2o)                                      \
    {                                                                         \
        f32x2 p0 = pkmax(pkmax(a0_01, a0_23), pkmax(a0_45, a0_67));           \
        f32x2 p1 = pkmax(pkmax(a1_01, a1_23), pkmax(a1_45, a1_67));           \
        f32x2 p2 = pkmax(pkmax(a2_01, a2_23), pkmax(a2_45, a2_67));           \
        mx0o = fmaxf(p0.x, p0.y);                                             \
        mx1o = fmaxf(p1.x, p1.y);                                             \
        mx2o = fmaxf(p2.x, p2.y);                                             \
    }

#define DECL_ACC                                                              \
    f32x2 a0_01 = {0.f,0.f}, a0_23 = {0.f,0.f}, a0_45 = {0.f,0.f}, a0_67 = {0.f,0.f}; \
    f32x2 a1_01 = {0.f,0.f}, a1_23 = {0.f,0.f}, a1_45 = {0.f,0.f}, a1_67 = {0.f,0.f}; \
    f32x2 a2_01 = {0.f,0.f}, a2_23 = {0.f,0.f}, a2_45 = {0.f,0.f}, a2_67 = {0.f,0.f};

// LDS operands stored PRE-DUPLICATED; hot loops DS-only (in-order lgkmcnt
// pipelining — r4 showed SMEM+DS mixing forces per-iter drains). unroll 2
// keeps the live set at ~40 VGPRs (r6 measurement).

// Depth-0: A,B block-uniform, fully packed from LDS.
__device__ __forceinline__ void density_max3_half_d0(
    const f32x4* __restrict__ sAB, const f32x4* __restrict__ sW01,
    const f32x2* __restrict__ sW2,
    float nears, float span, const float* __restrict__ jp, int kbase,
    float& mx0o, float& mx1o, float& mx2o)
{
    MAKE_Z(jp, kbase, nears, span)
    DECL_ACC
    #pragma unroll 2
    for (int j = 0; j < HID; ++j) {
        f32x4 ab  = sAB[j];    // {A,A,B,B}
        f32x4 w01 = sW01[j];   // {w20,w20,w21,w21}
        f32x2 w2  = sW2[j];    // {w22,w22}
        f32x2 A2 = {ab.x, ab.y}, B2 = {ab.z, ab.w};
        f32x2 W0 = {w01.x, w01.y}, W1 = {w01.z, w01.w};
        DENSITY_J_BODY(A2, B2, W0, W1, w2)
    }
    DENSITY_EPILOG(mx0o, mx1o, mx2o)
}

// Depth-1: o,d diverge -> A,B from pre-scaled w1 (6 fma) then broadcast.
__device__ __forceinline__ void density_max3_half_d1(
    const f32x4* __restrict__ sPW, const f32x4* __restrict__ sW01,
    const f32x2* __restrict__ sW2,
    float ox, float oy, float oz, float dx, float dy, float dz,
    float nears, float span, const float* __restrict__ jp, int kbase,
    float& mx0o, float& mx1o, float& mx2o)
{
    MAKE_Z(jp, kbase, nears, span)
    DECL_ACC
    #pragma unroll 2
    for (int j = 0; j < HID; ++j) {
        f32x4 pw  = sPW[j];    // {pw1x,pw1y,pw1z,-}
        f32x4 w01 = sW01[j];
        f32x2 w2  = sW2[j];
        float A = ox*pw.x + oy*pw.y + oz*pw.z;
        float B = dx*pw.x + dy*pw.y + dz*pw.z;
        f32x2 A2 = {A, A}, B2 = {B, B};
        f32x2 W0 = {w01.x, w01.y}, W1 = {w01.z, w01.w};
        DENSITY_J_BODY(A2, B2, W0, W1, w2)
    }
    DENSITY_EPILOG(mx0o, mx1o, mx2o)
}

__device__ __forceinline__ void env_logv(
    const float* __restrict__ env_map,
    float px, float py, float pz,
    float& v0, float& v1, float& v2)
{
    float theta = atan2f(px, -pz) * (1.0f/3.14159265358979323846f);
    float acv = (fabsf(py) <= 1.0f) ? acosf(py) : 0.0f;  // nan_to_num(arccos)
    float phi = 0.63661977236758134308f * acv - 1.0f;    // 2/pi
    float ixf = ((theta + 1.0f)*256.0f - 1.0f)*0.5f;
    float iyf = ((phi   + 1.0f)*128.0f - 1.0f)*0.5f;
    float x0f = floorf(ixf), y0f = floorf(iyf);
    float wx = ixf - x0f, wy = iyf - y0f;
    v0 = 0.f; v1 = 0.f; v2 = 0.f;
    auto tap = [&](float xc, float yc, float w) {
        if (xc >= 0.0f && xc < 256.0f && yc >= 0.0f && yc < 128.0f) {
            int xi = (int)xc, yi = (int)yc;
            const float* e = env_map + yi*256 + xi;
            v0 += w * e[0];
            v1 += w * e[128*256];
            v2 += w * e[2*128*256];
        }
    };
    tap(x0f,      y0f,      (1.0f-wx)*(1.0f-wy));
    tap(x0f+1.0f, y0f,      wx*(1.0f-wy));
    tap(x0f,      y0f+1.0f, (1.0f-wx)*wy);
    tap(x0f+1.0f, y0f+1.0f, wx*wy);
}

// 256 threads/block = 1 ray; lane pair (2s,2s+1) shares sub-ray s.
// NO waves-per-eu constraint: (256,6) capped residency at 6 blocks/CU
// (grid = 8 blocks/CU of work -> tail; occupancy 43%), and (256,8)
// collapses the allocator (VGPR=32, 20+ MB spills — r3/r5/r7). Natural
// allocation is ~40 VGPR (r6) -> HW allows the full 8 blocks/CU.
__global__ __launch_bounds__(256)
void render_kernel(const float* __restrict__ rays_o,
                   const float* __restrict__ rays_d,
                   const float* __restrict__ env_map,
                   const float* __restrict__ Wd1,
                   const float* __restrict__ Wd2,
                   const float* __restrict__ Wf1,
                   const float* __restrict__ Ws,
                   const float* __restrict__ Wdir,
                   const float* __restrict__ Wrho,
                   const float* __restrict__ jitter,
                   const float* __restrict__ u_t,
                   const float* __restrict__ u_scatter,
                   const int*   __restrict__ channel,
                   float* __restrict__ out)
{
    const int ray  = blockIdx.x;
    const int tid  = threadIdx.x;
    const int s    = tid >> 1;
    const int half = tid & 1;
    const int m    = ray * TOT + s;
    const int kbase = half * 8;

    __shared__ f32x4 sAB[HID];     // {A,A,B,B}
    __shared__ f32x4 sW01[HID];    // {w20,w20,w21,w21}
    __shared__ f32x2 sW2[HID];     // {w22,w22}
    __shared__ f32x4 sPW[HID];     // {pw1x,pw1y,pw1z,0}
    __shared__ float sred[4][3];

    float ox = rays_o[ray*3+0], oy = rays_o[ray*3+1], oz = rays_o[ray*3+2];
    float dx = rays_d[ray*3+0], dy = rays_d[ray*3+1], dz = rays_d[ray*3+2];

    // ---- per-block tables (block-uniform depth-0 geometry) ----
    if (tid < HID) {
        const float INV2PI = 0.15915494309189535f;
        float w1x = Wd1[tid], w1y = Wd1[HID+tid], w1z = Wd1[2*HID+tid];
        float pw1x = w1x*INV2PI, pw1y = w1y*INV2PI, pw1z = w1z*INV2PI;
        float A = ox*pw1x + oy*pw1y + oz*pw1z;
        float B = dx*pw1x + dy*pw1y + dz*pw1z;
        float w20 = Wd2[3*tid], w21 = Wd2[3*tid+1], w22 = Wd2[3*tid+2];
        sAB[tid]  = (f32x4){A, A, B, B};
        sW01[tid] = (f32x4){w20, w20, w21, w21};
        sW2[tid]  = (f32x2){w22, w22};
        sPW[tid]  = (f32x4){pw1x, pw1y, pw1z, 0.0f};
    }
    __syncthreads();

    float thr0 = 1.f, thr1 = 1.f, thr2 = 1.f;
    float rgb0 = 0.f, rgb1 = 0.f, rgb2 = 0.f;
    bool alive;

    // ================= depth 0 =================
    {
        float a = dx*dx + dy*dy + dz*dz;
        float b = 2.0f*(dx*ox + dy*oy + dz*oz);
        float c = (ox*ox + oy*oy + oz*oz) - 1.0f;
        float delta = b*b - 4.0f*a*c;
        alive = (delta > 0.0f);
        if (alive) {
            float sq    = sqrtf(delta);
            float nears = fmaxf((-b - sq) / (2.0f*a), 0.001f);
            float fars  = fmaxf((-b + sq) / (2.0f*a), 0.001f);
            float span  = fars - nears;

            float mx0, mx1, mx2;
            density_max3_half_d0(sAB, sW01, sW2, nears, span,
                                 jitter + (size_t)m*INDS + kbase, kbase,
                                 mx0,mx1,mx2);
            mx0 = fmaxf(mx0, __shfl_xor(mx0, 1, 64));
            mx1 = fmaxf(mx1, __shfl_xor(mx1, 1, 64));
            mx2 = fmaxf(mx2, __shfl_xor(mx2, 1, 64));

            float maj0 = fmaxf(softplus_f(mx0), 0.001f);
            float maj1 = fmaxf(softplus_f(mx1), 0.001f);
            float maj2 = fmaxf(softplus_f(mx2), 0.001f);
            float mmax = fmaxf(fmaxf(maj0, maj1), maj2);

            int   ch  = channel[m];
            float maj = (ch == 0) ? maj0 : ((ch == 1) ? maj1 : maj2);
            float t   = -log1pf(-u_t[m]) / maj + nears;

            if (t >= fars) {
                float den0 = __expf(-maj0*span)/(mmax+EPSF) + EPSF;
                float den1 = __expf(-maj1*span)/(mmax+EPSF) + EPSF;
                float den2 = __expf(-maj2*span)/(mmax+EPSF) + EPSF;
                float idm = 3.0f / (den0+den1+den2);
                float v0,v1,v2;
                env_logv(env_map, fmaf(dx,fars,ox), fmaf(dy,fars,oy), fmaf(dz,fars,oz), v0,v1,v2);
                rgb0 = den0*idm*__expf(v0);
                rgb1 = den1*idm*__expf(v1);
                rgb2 = den2*idm*__expf(v2);
                alive = false;
            } else {
                float tn  = t - nears;
                float imm = 1.0f / mmax;
                float tr0 = __expf(-maj0*tn) * imm;
                float tr1 = __expf(-maj1*tn) * imm;
                float tr2 = __expf(-maj2*tn) * imm;
                float i2m = 3.0f / (maj0*tr0 + maj1*tr1 + maj2*tr2);
                thr0 = tr0 * i2m;   // thr was 1
                thr1 = tr1 * i2m;
                thr2 = tr2 * i2m;
                ox = fmaf(dx, t, ox); oy = fmaf(dy, t, oy); oz = fmaf(dz, t, oz);

                // material MLP, hidden dim split across the lane pair
                float st0=0.f, st1=0.f, st2=0.f;
                float dn0=0.f, dn1=0.f, dn2v=0.f;
                float rh0=0.f, rh1=0.f, rh2=0.f;
                const int j0 = half * 32;
                #pragma unroll 2
                for (int j = j0; j < j0 + 32; ++j) {
                    float pre = ox*Wf1[j] + oy*Wf1[HID+j] + oz*Wf1[2*HID+j]
                              + dx*Wf1[3*HID+j] + dy*Wf1[4*HID+j] + dz*Wf1[5*HID+j];
                    float f = tanh_fast(pre);
                    st0  = fmaf(f, Ws[j*3+0], st0);
                    st1  = fmaf(f, Ws[j*3+1], st1);
                    st2  = fmaf(f, Ws[j*3+2], st2);
                    dn0  = fmaf(f, Wdir[j*3+0], dn0);
                    dn1  = fmaf(f, Wdir[j*3+1], dn1);
                    dn2v = fmaf(f, Wdir[j*3+2], dn2v);
                    rh0  = fmaf(f, Wrho[j*3+0], rh0);
                    rh1  = fmaf(f, Wrho[j*3+1], rh1);
                    rh2  = fmaf(f, Wrho[j*3+2], rh2);
                }
                st0  += __shfl_xor(st0, 1, 64);
                st1  += __shfl_xor(st1, 1, 64);
                st2  += __shfl_xor(st2, 1, 64);
                dn0  += __shfl_xor(dn0, 1, 64);
                dn1  += __shfl_xor(dn1, 1, 64);
                dn2v += __shfl_xor(dn2v, 1, 64);
                rh0  += __shfl_xor(rh0, 1, 64);
                rh1  += __shfl_xor(rh1, 1, 64);
                rh2  += __shfl_xor(rh2, 1, 64);

                float stch = (ch == 0) ? st0 : ((ch == 1) ? st1 : st2);
                float sp = fminf(softplus_f(stch) / maj, 1.0f);
                if (u_scatter[m] < sp) {
                    float inr = 1.0f / (sqrtf(dn0*dn0 + dn1*dn1 + dn2v*dn2v) + EPSF);
                    dx = dn0*inr; dy = dn1*inr; dz = dn2v*inr;
                    float isp = 1.0f/(sp + EPSF);
                    thr0 *= isp * sigmoid_f(rh0);
                    thr1 *= isp * sigmoid_f(rh1);
                    thr2 *= isp * sigmoid_f(rh2);
                } else {
                    float iv = 1.0f/(1.0f - sp + EPSF);
                    thr0 *= iv; thr1 *= iv; thr2 *= iv;
                }
            }
        }
    }

    // ================= depth 1 (t = fars -> hit if delta>0) =================
    if (alive) {
        float a = dx*dx + dy*dy + dz*dz;
        float b = 2.0f*(dx*ox + dy*oy + dz*oz);
        float c = (ox*ox + oy*oy + oz*oz) - 1.0f;
        float delta = b*b - 4.0f*a*c;
        if (delta > 0.0f) {
            float sq    = sqrtf(delta);
            float nears = fmaxf((-b - sq) / (2.0f*a), 0.001f);
            float fars  = fmaxf((-b + sq) / (2.0f*a), 0.001f);
            float span  = fars - nears;

            float mx0, mx1, mx2;
            density_max3_half_d1(sPW, sW01, sW2, ox,oy,oz, dx,dy,dz, nears, span,
                                 jitter + ((size_t)MTOT + m)*INDS + kbase, kbase,
                                 mx0,mx1,mx2);
            mx0 = fmaxf(mx0, __shfl_xor(mx0, 1, 64));
            mx1 = fmaxf(mx1, __shfl_xor(mx1, 1, 64));
            mx2 = fmaxf(mx2, __shfl_xor(mx2, 1, 64));

            float maj0 = fmaxf(softplus_f(mx0), 0.001f);
            float maj1 = fmaxf(softplus_f(mx1), 0.001f);
            float maj2 = fmaxf(softplus_f(mx2), 0.001f);
            float mmax = fmaxf(fmaxf(maj0, maj1), maj2);

            float den0 = __expf(-maj0*span)/(mmax+EPSF) + EPSF;
            float den1 = __expf(-maj1*span)/(mmax+EPSF) + EPSF;
            float den2 = __expf(-maj2*span)/(mmax+EPSF) + EPSF;
            float idm = 3.0f / (den0+den1+den2);
            float v0,v1,v2;
            env_logv(env_map, fmaf(dx,fars,ox), fmaf(dy,fars,oy), fmaf(dz,fars,oz), v0,v1,v2);
            rgb0 += thr0 * den0*idm*__expf(v0);
            rgb1 += thr1 * den1*idm*__expf(v1);
            rgb2 += thr2 * den2*idm*__expf(v2);
        }
    }

    // ---- reduction: each sub-ray duplicated x2 -> sum/256 == mean/128 ----
    float r0 = rgb0, r1 = rgb1, r2 = rgb2;
    #pragma unroll
    for (int off = 32; off > 0; off >>= 1) {
        r0 += __shfl_down(r0, off, 64);
        r1 += __shfl_down(r1, off, 64);
        r2 += __shfl_down(r2, off, 64);
    }
    int wave = tid >> 6;
    if ((tid & 63) == 0) {
        sred[wave][0] = r0; sred[wave][1] = r1; sred[wave][2] = r2;
    }
    __syncthreads();
    if (tid == 0) {
        out[ray*3+0] = (sred[0][0]+sred[1][0]+sred[2][0]+sred[3][0]) * (1.0f/256.0f);
        out[ray*3+1] = (sred[0][1]+sred[1][1]+sred[2][1]+sred[3][1]) * (1.0f/256.0f);
        out[ray*3+2] = (sred[0][2]+sred[1][2]+sred[2][2]+sred[3][2]) * (1.0f/256.0f);
    }
}

extern "C" void kernel_launch(void* const* d_in, const int* in_sizes, int n_in,
                              void* d_out, int out_size, void* d_ws, size_t ws_size,
                              hipStream_t stream) {
    const float* rays_o    = (const float*)d_in[0];
    const float* rays_d    = (const float*)d_in[1];
    const float* env_map   = (const float*)d_in[2];
    const float* Wd1       = (const float*)d_in[3];
    const float* Wd2       = (const float*)d_in[4];
    const float* Wf1       = (const float*)d_in[5];
    const float* Ws        = (const float*)d_in[6];
    const float* Wdir      = (const float*)d_in[7];
    const float* Wrho      = (const float*)d_in[8];
    const float* jitter    = (const float*)d_in[9];
    const float* u_t       = (const float*)d_in[10];
    const float* u_scatter = (const float*)d_in[11];
    const int*   channel   = (const int*)d_in[12];
    float* out = (float*)d_out;

    render_kernel<<<dim3(NRAYS), dim3(256), 0, stream>>>(
        rays_o, rays_d, env_map, Wd1, Wd2, Wf1, Ws, Wdir, Wrho,
        jitter, u_t, u_scatter, channel, out);
}

// Round 9
// 208.265 us; speedup vs baseline: 1.0325x; 1.0272x over previous
//
#include <hip/hip_runtime.h>
#include <math.h>

#define NRAYS 2048
#define TOT   128
#define INDS  16
#define HID   64
#define EPSF  1e-8f
#define MTOT  (NRAYS*TOT)

typedef float f32x2 __attribute__((ext_vector_type(2)));
typedef float f32x4 __attribute__((ext_vector_type(4)));

__device__ __forceinline__ float softplus_f(float x) {
    return fmaxf(x, 0.0f) + __logf(1.0f + __expf(-fabsf(x)));
}
__device__ __forceinline__ float sigmoid_f(float x) {
    return 1.0f / (1.0f + __expf(-x));
}
__device__ __forceinline__ float tanh_fast(float x) {
    float e2 = __expf(2.0f * x);
    return 1.0f - 2.0f / (e2 + 1.0f);
}
__device__ __forceinline__ f32x2 pkmax(f32x2 a, f32x2 b) {
    f32x2 r; r.x = fmaxf(a.x, b.x); r.y = fmaxf(a.y, b.y); return r;
}

// z_k = nears + span*(k/15) + (j_k-0.5)*span/16
//     = fma(j_k, span/16, fma(span, k/15 - 1/32, nears))   [2 fma/sample]
// CK(i) must be a compile-time constant.
#define CK(i) ((float)(i)*(1.0f/15.0f) - 0.03125f)

// Build the 8 jittered z samples for this half from PRELOADED jitter regs.
#define MAKE_Z(jA, jB, kbase, nears, span)                                    \
    float s16 = (span) * (1.0f/16.0f);                                        \
    f32x2 z01, z23, z45, z67;                                                 \
    z01.x = fmaf((jA).x, s16, fmaf(span, CK((kbase)+0), nears));              \
    z01.y = fmaf((jA).y, s16, fmaf(span, CK((kbase)+1), nears));              \
    z23.x = fmaf((jA).z, s16, fmaf(span, CK((kbase)+2), nears));              \
    z23.y = fmaf((jA).w, s16, fmaf(span, CK((kbase)+3), nears));              \
    z45.x = fmaf((jB).x, s16, fmaf(span, CK((kbase)+4), nears));              \
    z45.y = fmaf((jB).y, s16, fmaf(span, CK((kbase)+5), nears));              \
    z67.x = fmaf((jB).z, s16, fmaf(span, CK((kbase)+6), nears));              \
    z67.y = fmaf((jB).w, s16, fmaf(span, CK((kbase)+7), nears));

// Inner body given packed A2,B2 and packed weight pairs W0,W1,W2v.
#define DENSITY_J_BODY(A2, B2, W0, W1, W2v)                                   \
    {                                                                         \
        f32x2 g01 = z01*(B2) + (A2);                                          \
        f32x2 g23 = z23*(B2) + (A2);                                          \
        f32x2 g45 = z45*(B2) + (A2);                                          \
        f32x2 g67 = z67*(B2) + (A2);                                          \
        f32x2 h01, h23, h45, h67;                                             \
        h01.x = __builtin_amdgcn_sinf(g01.x); h01.y = __builtin_amdgcn_sinf(g01.y); \
        h23.x = __builtin_amdgcn_sinf(g23.x); h23.y = __builtin_amdgcn_sinf(g23.y); \
        h45.x = __builtin_amdgcn_sinf(g45.x); h45.y = __builtin_amdgcn_sinf(g45.y); \
        h67.x = __builtin_amdgcn_sinf(g67.x); h67.y = __builtin_amdgcn_sinf(g67.y); \
        a0_01 += h01*(W0); a0_23 += h23*(W0); a0_45 += h45*(W0); a0_67 += h67*(W0); \
        a1_01 += h01*(W1); a1_23 += h23*(W1); a1_45 += h45*(W1); a1_67 += h67*(W1); \
        a2_01 += h01*(W2v); a2_23 += h23*(W2v); a2_45 += h45*(W2v); a2_67 += h67*(W2v); \
    }

#define DENSITY_EPILOG(mx0o, mx1o, mx2o)                                      \
    {                                                                         \
        f32x2 p0 = pkmax(pkmax(a0_01, a0_23), pkmax(a0_45, a0_67));           \
        f32x2 p1 = pkmax(pkmax(a1_01, a1_23), pkmax(a1_45, a1_67));           \
        f32x2 p2 = pkmax(pkmax(a2_01, a2_23), pkmax(a2_45, a2_67));           \
        mx0o = fmaxf(p0.x, p0.y);                                             \
        mx1o = fmaxf(p1.x, p1.y);                                             \
        mx2o = fmaxf(p2.x, p2.y);                                             \
    }

#define DECL_ACC                                                              \
    f32x2 a0_01 = {0.f,0.f}, a0_23 = {0.f,0.f}, a0_45 = {0.f,0.f}, a0_67 = {0.f,0.f}; \
    f32x2 a1_01 = {0.f,0.f}, a1_23 = {0.f,0.f}, a1_45 = {0.f,0.f}, a1_67 = {0.f,0.f}; \
    f32x2 a2_01 = {0.f,0.f}, a2_23 = {0.f,0.f}, a2_45 = {0.f,0.f}, a2_67 = {0.f,0.f};

// LDS operands PRE-DUPLICATED; hot loops DS-only (r4: SMEM+DS mixing forces
// per-iter lgkmcnt drains). unroll 2 keeps live set small (r6: 40 VGPR).

// Depth-0: A,B block-uniform, fully packed from LDS. Jitter PRELOADED.
__device__ __forceinline__ void density_max3_half_d0(
    const f32x4* __restrict__ sAB, const f32x4* __restrict__ sW01,
    const f32x2* __restrict__ sW2,
    float nears, float span, float4 jA, float4 jB, int kbase,
    float& mx0o, float& mx1o, float& mx2o)
{
    MAKE_Z(jA, jB, kbase, nears, span)
    DECL_ACC
    #pragma unroll 2
    for (int j = 0; j < HID; ++j) {
        f32x4 ab  = sAB[j];    // {A,A,B,B}
        f32x4 w01 = sW01[j];   // {w20,w20,w21,w21}
        f32x2 w2  = sW2[j];    // {w22,w22}
        f32x2 A2 = {ab.x, ab.y}, B2 = {ab.z, ab.w};
        f32x2 W0 = {w01.x, w01.y}, W1 = {w01.z, w01.w};
        DENSITY_J_BODY(A2, B2, W0, W1, w2)
    }
    DENSITY_EPILOG(mx0o, mx1o, mx2o)
}

// Depth-1: o,d diverge -> A,B from pre-scaled w1 (6 fma). Jitter PRELOADED
// at kernel entry so the HBM latency hides under the whole depth-0 body.
__device__ __forceinline__ void density_max3_half_d1(
    const f32x4* __restrict__ sPW, const f32x4* __restrict__ sW01,
    const f32x2* __restrict__ sW2,
    float ox, float oy, float oz, float dx, float dy, float dz,
    float nears, float span, float4 jA, float4 jB, int kbase,
    float& mx0o, float& mx1o, float& mx2o)
{
    MAKE_Z(jA, jB, kbase, nears, span)
    DECL_ACC
    #pragma unroll 2
    for (int j = 0; j < HID; ++j) {
        f32x4 pw  = sPW[j];    // {pw1x,pw1y,pw1z,-}
        f32x4 w01 = sW01[j];
        f32x2 w2  = sW2[j];
        float A = ox*pw.x + oy*pw.y + oz*pw.z;
        float B = dx*pw.x + dy*pw.y + dz*pw.z;
        f32x2 A2 = {A, A}, B2 = {B, B};
        f32x2 W0 = {w01.x, w01.y}, W1 = {w01.z, w01.w};
        DENSITY_J_BODY(A2, B2, W0, W1, w2)
    }
    DENSITY_EPILOG(mx0o, mx1o, mx2o)
}

__device__ __forceinline__ void env_logv(
    const float* __restrict__ env_map,
    float px, float py, float pz,
    float& v0, float& v1, float& v2)
{
    float theta = atan2f(px, -pz) * (1.0f/3.14159265358979323846f);
    float acv = (fabsf(py) <= 1.0f) ? acosf(py) : 0.0f;  // nan_to_num(arccos)
    float phi = 0.63661977236758134308f * acv - 1.0f;    // 2/pi
    float ixf = ((theta + 1.0f)*256.0f - 1.0f)*0.5f;
    float iyf = ((phi   + 1.0f)*128.0f - 1.0f)*0.5f;
    float x0f = floorf(ixf), y0f = floorf(iyf);
    float wx = ixf - x0f, wy = iyf - y0f;
    v0 = 0.f; v1 = 0.f; v2 = 0.f;
    auto tap = [&](float xc, float yc, float w) {
        if (xc >= 0.0f && xc < 256.0f && yc >= 0.0f && yc < 128.0f) {
            int xi = (int)xc, yi = (int)yc;
            const float* e = env_map + yi*256 + xi;
            v0 += w * e[0];
            v1 += w * e[128*256];
            v2 += w * e[2*128*256];
        }
    };
    tap(x0f,      y0f,      (1.0f-wx)*(1.0f-wy));
    tap(x0f+1.0f, y0f,      wx*(1.0f-wy));
    tap(x0f,      y0f+1.0f, (1.0f-wx)*wy);
    tap(x0f+1.0f, y0f+1.0f, wx*wy);
}

// 256 threads/block = 1 ray; lane pair (2s,2s+1) shares sub-ray s.
// No waves-per-eu constraint (r3/r5/r7: forcing 8/SIMD collapses the
// allocator to 32 VGPR + 20 MB spills; r8: natural = 40 VGPR).
// NEW (r9): all per-thread global inputs prefetched at kernel entry —
// depth-1's 16 MB jitter demand-load was a synchronized ~900-cyc stall
// for every wave mid-kernel; now it hides under depth-0 (~50 us).
__global__ __launch_bounds__(256)
void render_kernel(const float* __restrict__ rays_o,
                   const float* __restrict__ rays_d,
                   const float* __restrict__ env_map,
                   const float* __restrict__ Wd1,
                   const float* __restrict__ Wd2,
                   const float* __restrict__ Wf1,
                   const float* __restrict__ Ws,
                   const float* __restrict__ Wdir,
                   const float* __restrict__ Wrho,
                   const float* __restrict__ jitter,
                   const float* __restrict__ u_t,
                   const float* __restrict__ u_scatter,
                   const int*   __restrict__ channel,
                   float* __restrict__ out)
{
    const int ray  = blockIdx.x;
    const int tid  = threadIdx.x;
    const int s    = tid >> 1;
    const int half = tid & 1;
    const int m    = ray * TOT + s;
    const int kbase = half * 8;

    __shared__ f32x4 sAB[HID];     // {A,A,B,B}
    __shared__ f32x4 sW01[HID];    // {w20,w20,w21,w21}
    __shared__ f32x2 sW2[HID];     // {w22,w22}
    __shared__ f32x4 sPW[HID];     // {pw1x,pw1y,pw1z,0}
    __shared__ float sred[4][3];

    // ---- prefetch ALL per-thread globals up front (loads go in flight
    // now; first use of d1 jitter is ~50 us later) ----
    const float4* j0p = (const float4*)(jitter + (size_t)m*INDS + kbase);
    const float4* j1p = (const float4*)(jitter + ((size_t)MTOT + m)*INDS + kbase);
    float4 j0A = j0p[0], j0B = j0p[1];
    float4 j1A = j1p[0], j1B = j1p[1];
    int   ch = channel[m];
    float ut = u_t[m];
    float us = u_scatter[m];

    float ox = rays_o[ray*3+0], oy = rays_o[ray*3+1], oz = rays_o[ray*3+2];
    float dx = rays_d[ray*3+0], dy = rays_d[ray*3+1], dz = rays_d[ray*3+2];

    // ---- per-block tables (block-uniform depth-0 geometry) ----
    if (tid < HID) {
        const float INV2PI = 0.15915494309189535f;
        float w1x = Wd1[tid], w1y = Wd1[HID+tid], w1z = Wd1[2*HID+tid];
        float pw1x = w1x*INV2PI, pw1y = w1y*INV2PI, pw1z = w1z*INV2PI;
        float A = ox*pw1x + oy*pw1y + oz*pw1z;
        float B = dx*pw1x + dy*pw1y + dz*pw1z;
        float w20 = Wd2[3*tid], w21 = Wd2[3*tid+1], w22 = Wd2[3*tid+2];
        sAB[tid]  = (f32x4){A, A, B, B};
        sW01[tid] = (f32x4){w20, w20, w21, w21};
        sW2[tid]  = (f32x2){w22, w22};
        sPW[tid]  = (f32x4){pw1x, pw1y, pw1z, 0.0f};
    }
    __syncthreads();

    float thr0 = 1.f, thr1 = 1.f, thr2 = 1.f;
    float rgb0 = 0.f, rgb1 = 0.f, rgb2 = 0.f;
    bool alive;

    // ================= depth 0 =================
    {
        float a = dx*dx + dy*dy + dz*dz;
        float b = 2.0f*(dx*ox + dy*oy + dz*oz);
        float c = (ox*ox + oy*oy + oz*oz) - 1.0f;
        float delta = b*b - 4.0f*a*c;
        alive = (delta > 0.0f);
        if (alive) {
            float sq    = sqrtf(delta);
            float nears = fmaxf((-b - sq) / (2.0f*a), 0.001f);
            float fars  = fmaxf((-b + sq) / (2.0f*a), 0.001f);
            float span  = fars - nears;

            float mx0, mx1, mx2;
            density_max3_half_d0(sAB, sW01, sW2, nears, span,
                                 j0A, j0B, kbase, mx0,mx1,mx2);
            mx0 = fmaxf(mx0, __shfl_xor(mx0, 1, 64));
            mx1 = fmaxf(mx1, __shfl_xor(mx1, 1, 64));
            mx2 = fmaxf(mx2, __shfl_xor(mx2, 1, 64));

            float maj0 = fmaxf(softplus_f(mx0), 0.001f);
            float maj1 = fmaxf(softplus_f(mx1), 0.001f);
            float maj2 = fmaxf(softplus_f(mx2), 0.001f);
            float mmax = fmaxf(fmaxf(maj0, maj1), maj2);

            float maj = (ch == 0) ? maj0 : ((ch == 1) ? maj1 : maj2);
            float t   = -log1pf(-ut) / maj + nears;

            if (t >= fars) {
                float den0 = __expf(-maj0*span)/(mmax+EPSF) + EPSF;
                float den1 = __expf(-maj1*span)/(mmax+EPSF) + EPSF;
                float den2 = __expf(-maj2*span)/(mmax+EPSF) + EPSF;
                float idm = 3.0f / (den0+den1+den2);
                float v0,v1,v2;
                env_logv(env_map, fmaf(dx,fars,ox), fmaf(dy,fars,oy), fmaf(dz,fars,oz), v0,v1,v2);
                rgb0 = den0*idm*__expf(v0);
                rgb1 = den1*idm*__expf(v1);
                rgb2 = den2*idm*__expf(v2);
                alive = false;
            } else {
                float tn  = t - nears;
                float imm = 1.0f / mmax;
                float tr0 = __expf(-maj0*tn) * imm;
                float tr1 = __expf(-maj1*tn) * imm;
                float tr2 = __expf(-maj2*tn) * imm;
                float i2m = 3.0f / (maj0*tr0 + maj1*tr1 + maj2*tr2);
                thr0 = tr0 * i2m;   // thr was 1
                thr1 = tr1 * i2m;
                thr2 = tr2 * i2m;
                ox = fmaf(dx, t, ox); oy = fmaf(dy, t, oy); oz = fmaf(dz, t, oz);

                // material MLP, hidden dim split across the lane pair
                float st0=0.f, st1=0.f, st2=0.f;
                float dn0=0.f, dn1=0.f, dn2v=0.f;
                float rh0=0.f, rh1=0.f, rh2=0.f;
                const int j0 = half * 32;
                #pragma unroll 2
                for (int j = j0; j < j0 + 32; ++j) {
                    float pre = ox*Wf1[j] + oy*Wf1[HID+j] + oz*Wf1[2*HID+j]
                              + dx*Wf1[3*HID+j] + dy*Wf1[4*HID+j] + dz*Wf1[5*HID+j];
                    float f = tanh_fast(pre);
                    st0  = fmaf(f, Ws[j*3+0], st0);
                    st1  = fmaf(f, Ws[j*3+1], st1);
                    st2  = fmaf(f, Ws[j*3+2], st2);
                    dn0  = fmaf(f, Wdir[j*3+0], dn0);
                    dn1  = fmaf(f, Wdir[j*3+1], dn1);
                    dn2v = fmaf(f, Wdir[j*3+2], dn2v);
                    rh0  = fmaf(f, Wrho[j*3+0], rh0);
                    rh1  = fmaf(f, Wrho[j*3+1], rh1);
                    rh2  = fmaf(f, Wrho[j*3+2], rh2);
                }
                st0  += __shfl_xor(st0, 1, 64);
                st1  += __shfl_xor(st1, 1, 64);
                st2  += __shfl_xor(st2, 1, 64);
                dn0  += __shfl_xor(dn0, 1, 64);
                dn1  += __shfl_xor(dn1, 1, 64);
                dn2v += __shfl_xor(dn2v, 1, 64);
                rh0  += __shfl_xor(rh0, 1, 64);
                rh1  += __shfl_xor(rh1, 1, 64);
                rh2  += __shfl_xor(rh2, 1, 64);

                float stch = (ch == 0) ? st0 : ((ch == 1) ? st1 : st2);
                float sp = fminf(softplus_f(stch) / maj, 1.0f);
                if (us < sp) {
                    float inr = 1.0f / (sqrtf(dn0*dn0 + dn1*dn1 + dn2v*dn2v) + EPSF);
                    dx = dn0*inr; dy = dn1*inr; dz = dn2v*inr;
                    float isp = 1.0f/(sp + EPSF);
                    thr0 *= isp * sigmoid_f(rh0);
                    thr1 *= isp * sigmoid_f(rh1);
                    thr2 *= isp * sigmoid_f(rh2);
                } else {
                    float iv = 1.0f/(1.0f - sp + EPSF);
                    thr0 *= iv; thr1 *= iv; thr2 *= iv;
                }
            }
        }
    }

    // ================= depth 1 (t = fars -> hit if delta>0) =================
    if (alive) {
        float a = dx*dx + dy*dy + dz*dz;
        float b = 2.0f*(dx*ox + dy*oy + dz*oz);
        float c = (ox*ox + oy*oy + oz*oz) - 1.0f;
        float delta = b*b - 4.0f*a*c;
        if (delta > 0.0f) {
            float sq    = sqrtf(delta);
            float nears = fmaxf((-b - sq) / (2.0f*a), 0.001f);
            float fars  = fmaxf((-b + sq) / (2.0f*a), 0.001f);
            float span  = fars - nears;

            float mx0, mx1, mx2;
            density_max3_half_d1(sPW, sW01, sW2, ox,oy,oz, dx,dy,dz, nears, span,
                                 j1A, j1B, kbase, mx0,mx1,mx2);
            mx0 = fmaxf(mx0, __shfl_xor(mx0, 1, 64));
            mx1 = fmaxf(mx1, __shfl_xor(mx1, 1, 64));
            mx2 = fmaxf(mx2, __shfl_xor(mx2, 1, 64));

            float maj0 = fmaxf(softplus_f(mx0), 0.001f);
            float maj1 = fmaxf(softplus_f(mx1), 0.001f);
            float maj2 = fmaxf(softplus_f(mx2), 0.001f);
            float mmax = fmaxf(fmaxf(maj0, maj1), maj2);

            float den0 = __expf(-maj0*span)/(mmax+EPSF) + EPSF;
            float den1 = __expf(-maj1*span)/(mmax+EPSF) + EPSF;
            float den2 = __expf(-maj2*span)/(mmax+EPSF) + EPSF;
            float idm = 3.0f / (den0+den1+den2);
            float v0,v1,v2;
            env_logv(env_map, fmaf(dx,fars,ox), fmaf(dy,fars,oy), fmaf(dz,fars,oz), v0,v1,v2);
            rgb0 += thr0 * den0*idm*__expf(v0);
            rgb1 += thr1 * den1*idm*__expf(v1);
            rgb2 += thr2 * den2*idm*__expf(v2);
        }
    }

    // ---- reduction: each sub-ray duplicated x2 -> sum/256 == mean/128 ----
    float r0 = rgb0, r1 = rgb1, r2 = rgb2;
    #pragma unroll
    for (int off = 32; off > 0; off >>= 1) {
        r0 += __shfl_down(r0, off, 64);
        r1 += __shfl_down(r1, off, 64);
        r2 += __shfl_down(r2, off, 64);
    }
    int wave = tid >> 6;
    if ((tid & 63) == 0) {
        sred[wave][0] = r0; sred[wave][1] = r1; sred[wave][2] = r2;
    }
    __syncthreads();
    if (tid == 0) {
        out[ray*3+0] = (sred[0][0]+sred[1][0]+sred[2][0]+sred[3][0]) * (1.0f/256.0f);
        out[ray*3+1] = (sred[0][1]+sred[1][1]+sred[2][1]+sred[3][1]) * (1.0f/256.0f);
        out[ray*3+2] = (sred[0][2]+sred[1][2]+sred[2][2]+sred[3][2]) * (1.0f/256.0f);
    }
}

extern "C" void kernel_launch(void* const* d_in, const int* in_sizes, int n_in,
                              void* d_out, int out_size, void* d_ws, size_t ws_size,
                              hipStream_t stream) {
    const float* rays_o    = (const float*)d_in[0];
    const float* rays_d    = (const float*)d_in[1];
    const float* env_map   = (const float*)d_in[2];
    const float* Wd1       = (const float*)d_in[3];
    const float* Wd2       = (const float*)d_in[4];
    const float* Wf1       = (const float*)d_in[5];
    const float* Ws        = (const float*)d_in[6];
    const float* Wdir      = (const float*)d_in[7];
    const float* Wrho      = (const float*)d_in[8];
    const float* jitter    = (const float*)d_in[9];
    const float* u_t       = (const float*)d_in[10];
    const float* u_scatter = (const float*)d_in[11];
    const int*   channel   = (const int*)d_in[12];
    float* out = (float*)d_out;

    render_kernel<<<dim3(NRAYS), dim3(256), 0, stream>>>(
        rays_o, rays_d, env_map, Wd1, Wd2, Wf1, Ws, Wdir, Wrho,
        jitter, u_t, u_scatter, channel, out);
}

// Round 10
// 196.185 us; speedup vs baseline: 1.0960x; 1.0616x over previous
//
#include <hip/hip_runtime.h>
#include <math.h>

#define NRAYS 2048
#define TOT   128
#define INDS  16
#define HID   64
#define EPSF  1e-8f
#define MTOT  (NRAYS*TOT)

typedef float f32x2 __attribute__((ext_vector_type(2)));
typedef float f32x4 __attribute__((ext_vector_type(4)));

__device__ __forceinline__ float softplus_f(float x) {
    return fmaxf(x, 0.0f) + __logf(1.0f + __expf(-fabsf(x)));
}
__device__ __forceinline__ float sigmoid_f(float x) {
    return 1.0f / (1.0f + __expf(-x));
}
__device__ __forceinline__ float tanh_fast(float x) {
    float e2 = __expf(2.0f * x);
    return 1.0f - 2.0f / (e2 + 1.0f);
}
__device__ __forceinline__ f32x2 pkmax(f32x2 a, f32x2 b) {
    f32x2 r; r.x = fmaxf(a.x, b.x); r.y = fmaxf(a.y, b.y); return r;
}
// Guaranteed v_pk_fma_f32 (contraction-independent).
__device__ __forceinline__ f32x2 pkfma(f32x2 a, f32x2 b, f32x2 c) {
    return __builtin_elementwise_fma(a, b, c);
}

// z_k = fma(j_k, span/16, fma(span, k/15 - 1/32, nears))
#define CK(i) ((float)(i)*(1.0f/15.0f) - 0.03125f)

#define MAKE_Z(jA, jB, kbase, nears, span)                                    \
    float s16 = (span) * (1.0f/16.0f);                                        \
    f32x2 z01, z23, z45, z67;                                                 \
    z01.x = fmaf((jA).x, s16, fmaf(span, CK((kbase)+0), nears));              \
    z01.y = fmaf((jA).y, s16, fmaf(span, CK((kbase)+1), nears));              \
    z23.x = fmaf((jA).z, s16, fmaf(span, CK((kbase)+2), nears));              \
    z23.y = fmaf((jA).w, s16, fmaf(span, CK((kbase)+3), nears));              \
    z45.x = fmaf((jB).x, s16, fmaf(span, CK((kbase)+4), nears));              \
    z45.y = fmaf((jB).y, s16, fmaf(span, CK((kbase)+5), nears));              \
    z67.x = fmaf((jB).z, s16, fmaf(span, CK((kbase)+6), nears));              \
    z67.y = fmaf((jB).w, s16, fmaf(span, CK((kbase)+7), nears));

// Inner body: 16 v_pk_fma_f32 + 8 v_sin_f32 per j (was fmul+fadd pairs
// = up to 32 pk-ops/j if the compiler didn't contract).
#define DENSITY_J_BODY(A2, B2, W0, W1, W2v)                                   \
    {                                                                         \
        f32x2 g01 = pkfma(z01, (B2), (A2));                                   \
        f32x2 g23 = pkfma(z23, (B2), (A2));                                   \
        f32x2 g45 = pkfma(z45, (B2), (A2));                                   \
        f32x2 g67 = pkfma(z67, (B2), (A2));                                   \
        f32x2 h01, h23, h45, h67;                                             \
        h01.x = __builtin_amdgcn_sinf(g01.x); h01.y = __builtin_amdgcn_sinf(g01.y); \
        h23.x = __builtin_amdgcn_sinf(g23.x); h23.y = __builtin_amdgcn_sinf(g23.y); \
        h45.x = __builtin_amdgcn_sinf(g45.x); h45.y = __builtin_amdgcn_sinf(g45.y); \
        h67.x = __builtin_amdgcn_sinf(g67.x); h67.y = __builtin_amdgcn_sinf(g67.y); \
        a0_01 = pkfma(h01,(W0),a0_01); a0_23 = pkfma(h23,(W0),a0_23);         \
        a0_45 = pkfma(h45,(W0),a0_45); a0_67 = pkfma(h67,(W0),a0_67);         \
        a1_01 = pkfma(h01,(W1),a1_01); a1_23 = pkfma(h23,(W1),a1_23);         \
        a1_45 = pkfma(h45,(W1),a1_45); a1_67 = pkfma(h67,(W1),a1_67);         \
        a2_01 = pkfma(h01,(W2v),a2_01); a2_23 = pkfma(h23,(W2v),a2_23);       \
        a2_45 = pkfma(h45,(W2v),a2_45); a2_67 = pkfma(h67,(W2v),a2_67);       \
    }

#define DENSITY_EPILOG(mx0o, mx1o, mx2o)                                      \
    {                                                                         \
        f32x2 p0 = pkmax(pkmax(a0_01, a0_23), pkmax(a0_45, a0_67));           \
        f32x2 p1 = pkmax(pkmax(a1_01, a1_23), pkmax(a1_45, a1_67));           \
        f32x2 p2 = pkmax(pkmax(a2_01, a2_23), pkmax(a2_45, a2_67));           \
        mx0o = fmaxf(p0.x, p0.y);                                             \
        mx1o = fmaxf(p1.x, p1.y);                                             \
        mx2o = fmaxf(p2.x, p2.y);                                             \
    }

#define DECL_ACC                                                              \
    f32x2 a0_01 = {0.f,0.f}, a0_23 = {0.f,0.f}, a0_45 = {0.f,0.f}, a0_67 = {0.f,0.f}; \
    f32x2 a1_01 = {0.f,0.f}, a1_23 = {0.f,0.f}, a1_45 = {0.f,0.f}, a1_67 = {0.f,0.f}; \
    f32x2 a2_01 = {0.f,0.f}, a2_23 = {0.f,0.f}, a2_45 = {0.f,0.f}, a2_67 = {0.f,0.f};

// Depth-0: A,B block-uniform, fully packed from LDS. Jitter PRELOADED.
__device__ __forceinline__ void density_max3_half_d0(
    const f32x4* __restrict__ sAB, const f32x4* __restrict__ sW01,
    const f32x2* __restrict__ sW2,
    float nears, float span, float4 jA, float4 jB, int kbase,
    float& mx0o, float& mx1o, float& mx2o)
{
    MAKE_Z(jA, jB, kbase, nears, span)
    DECL_ACC
    #pragma unroll 2
    for (int j = 0; j < HID; ++j) {
        f32x4 ab  = sAB[j];    // {A,A,B,B}
        f32x4 w01 = sW01[j];   // {w20,w20,w21,w21}
        f32x2 w2  = sW2[j];    // {w22,w22}
        f32x2 A2 = {ab.x, ab.y}, B2 = {ab.z, ab.w};
        f32x2 W0 = {w01.x, w01.y}, W1 = {w01.z, w01.w};
        DENSITY_J_BODY(A2, B2, W0, W1, w2)
    }
    DENSITY_EPILOG(mx0o, mx1o, mx2o)
}

// Depth-1: o,d diverge -> A,B from pre-scaled w1 (6 fma) then broadcast.
__device__ __forceinline__ void density_max3_half_d1(
    const f32x4* __restrict__ sPW, const f32x4* __restrict__ sW01,
    const f32x2* __restrict__ sW2,
    float ox, float oy, float oz, float dx, float dy, float dz,
    float nears, float span, float4 jA, float4 jB, int kbase,
    float& mx0o, float& mx1o, float& mx2o)
{
    MAKE_Z(jA, jB, kbase, nears, span)
    DECL_ACC
    #pragma unroll 2
    for (int j = 0; j < HID; ++j) {
        f32x4 pw  = sPW[j];    // {pw1x,pw1y,pw1z,-}
        f32x4 w01 = sW01[j];
        f32x2 w2  = sW2[j];
        float A = fmaf(ox, pw.x, fmaf(oy, pw.y, oz*pw.z));
        float B = fmaf(dx, pw.x, fmaf(dy, pw.y, dz*pw.z));
        f32x2 A2 = {A, A}, B2 = {B, B};
        f32x2 W0 = {w01.x, w01.y}, W1 = {w01.z, w01.w};
        DENSITY_J_BODY(A2, B2, W0, W1, w2)
    }
    DENSITY_EPILOG(mx0o, mx1o, mx2o)
}

__device__ __forceinline__ void env_logv(
    const float* __restrict__ env_map,
    float px, float py, float pz,
    float& v0, float& v1, float& v2)
{
    float theta = atan2f(px, -pz) * (1.0f/3.14159265358979323846f);
    float acv = (fabsf(py) <= 1.0f) ? acosf(py) : 0.0f;  // nan_to_num(arccos)
    float phi = 0.63661977236758134308f * acv - 1.0f;    // 2/pi
    float ixf = ((theta + 1.0f)*256.0f - 1.0f)*0.5f;
    float iyf = ((phi   + 1.0f)*128.0f - 1.0f)*0.5f;
    float x0f = floorf(ixf), y0f = floorf(iyf);
    float wx = ixf - x0f, wy = iyf - y0f;
    v0 = 0.f; v1 = 0.f; v2 = 0.f;
    auto tap = [&](float xc, float yc, float w) {
        if (xc >= 0.0f && xc < 256.0f && yc >= 0.0f && yc < 128.0f) {
            int xi = (int)xc, yi = (int)yc;
            const float* e = env_map + yi*256 + xi;
            v0 += w * e[0];
            v1 += w * e[128*256];
            v2 += w * e[2*128*256];
        }
    };
    tap(x0f,      y0f,      (1.0f-wx)*(1.0f-wy));
    tap(x0f+1.0f, y0f,      wx*(1.0f-wy));
    tap(x0f,      y0f+1.0f, (1.0f-wx)*wy);
    tap(x0f+1.0f, y0f+1.0f, wx*wy);
}

// 256 threads/block = 1 ray; lane pair (2s,2s+1) shares sub-ray s.
// No waves-per-eu constraint (forcing 8/SIMD collapses the allocator:
// r3/r5/r7). All per-thread globals prefetched at entry (r9: -5 us).
// NEW (r10): density accumulate forced to v_pk_fma_f32 via
// __builtin_elementwise_fma; material MLP reduced to pre=P+t*Q with
// block-uniform P,Q and made DS-only (weights staged in LDS).
__global__ __launch_bounds__(256)
void render_kernel(const float* __restrict__ rays_o,
                   const float* __restrict__ rays_d,
                   const float* __restrict__ env_map,
                   const float* __restrict__ Wd1,
                   const float* __restrict__ Wd2,
                   const float* __restrict__ Wf1,
                   const float* __restrict__ Ws,
                   const float* __restrict__ Wdir,
                   const float* __restrict__ Wrho,
                   const float* __restrict__ jitter,
                   const float* __restrict__ u_t,
                   const float* __restrict__ u_scatter,
                   const int*   __restrict__ channel,
                   float* __restrict__ out)
{
    const int ray  = blockIdx.x;
    const int tid  = threadIdx.x;
    const int s    = tid >> 1;
    const int half = tid & 1;
    const int m    = ray * TOT + s;
    const int kbase = half * 8;

    __shared__ f32x4 sAB[HID];     // {A,A,B,B}
    __shared__ f32x4 sW01[HID];    // {w20,w20,w21,w21}
    __shared__ f32x2 sW2[HID];     // {w22,w22}
    __shared__ f32x4 sPW[HID];     // {pw1x,pw1y,pw1z,0}
    __shared__ f32x4 sM0[HID];     // {P, Q, ws0, ws1}
    __shared__ f32x4 sM1[HID];     // {ws2, wd0, wd1, wd2}
    __shared__ f32x4 sM2[HID];     // {wr0, wr1, wr2, 0}
    __shared__ float sred[4][3];

    // ---- prefetch ALL per-thread globals up front ----
    const float4* j0p = (const float4*)(jitter + (size_t)m*INDS + kbase);
    const float4* j1p = (const float4*)(jitter + ((size_t)MTOT + m)*INDS + kbase);
    float4 j0A = j0p[0], j0B = j0p[1];
    float4 j1A = j1p[0], j1B = j1p[1];
    int   ch = channel[m];
    float ut = u_t[m];
    float us = u_scatter[m];

    float ox = rays_o[ray*3+0], oy = rays_o[ray*3+1], oz = rays_o[ray*3+2];
    float dx = rays_d[ray*3+0], dy = rays_d[ray*3+1], dz = rays_d[ray*3+2];

    // ---- per-block tables (block-uniform depth-0 geometry) ----
    if (tid < HID) {
        const float INV2PI = 0.15915494309189535f;
        float w1x = Wd1[tid], w1y = Wd1[HID+tid], w1z = Wd1[2*HID+tid];
        float pw1x = w1x*INV2PI, pw1y = w1y*INV2PI, pw1z = w1z*INV2PI;
        float A = ox*pw1x + oy*pw1y + oz*pw1z;
        float B = dx*pw1x + dy*pw1y + dz*pw1z;
        float w20 = Wd2[3*tid], w21 = Wd2[3*tid+1], w22 = Wd2[3*tid+2];
        sAB[tid]  = (f32x4){A, A, B, B};
        sW01[tid] = (f32x4){w20, w20, w21, w21};
        sW2[tid]  = (f32x2){w22, w22};
        sPW[tid]  = (f32x4){pw1x, pw1y, pw1z, 0.0f};
        // material: pre_j = P + t*Q (o = o0 + t*d0, d = d0 pre-scatter)
        float f0 = Wf1[tid],       f1 = Wf1[HID+tid],   f2 = Wf1[2*HID+tid];
        float f3 = Wf1[3*HID+tid], f4 = Wf1[4*HID+tid], f5 = Wf1[5*HID+tid];
        float P = ox*f0 + oy*f1 + oz*f2 + dx*f3 + dy*f4 + dz*f5;
        float Q = dx*f0 + dy*f1 + dz*f2;
        sM0[tid] = (f32x4){P, Q, Ws[3*tid], Ws[3*tid+1]};
        sM1[tid] = (f32x4){Ws[3*tid+2], Wdir[3*tid], Wdir[3*tid+1], Wdir[3*tid+2]};
        sM2[tid] = (f32x4){Wrho[3*tid], Wrho[3*tid+1], Wrho[3*tid+2], 0.0f};
    }
    __syncthreads();

    float thr0 = 1.f, thr1 = 1.f, thr2 = 1.f;
    float rgb0 = 0.f, rgb1 = 0.f, rgb2 = 0.f;
    bool alive;

    // ================= depth 0 =================
    {
        float a = dx*dx + dy*dy + dz*dz;
        float b = 2.0f*(dx*ox + dy*oy + dz*oz);
        float c = (ox*ox + oy*oy + oz*oz) - 1.0f;
        float delta = b*b - 4.0f*a*c;
        alive = (delta > 0.0f);
        if (alive) {
            float sq    = sqrtf(delta);
            float nears = fmaxf((-b - sq) / (2.0f*a), 0.001f);
            float fars  = fmaxf((-b + sq) / (2.0f*a), 0.001f);
            float span  = fars - nears;

            float mx0, mx1, mx2;
            density_max3_half_d0(sAB, sW01, sW2, nears, span,
                                 j0A, j0B, kbase, mx0,mx1,mx2);
            mx0 = fmaxf(mx0, __shfl_xor(mx0, 1, 64));
            mx1 = fmaxf(mx1, __shfl_xor(mx1, 1, 64));
            mx2 = fmaxf(mx2, __shfl_xor(mx2, 1, 64));

            float maj0 = fmaxf(softplus_f(mx0), 0.001f);
            float maj1 = fmaxf(softplus_f(mx1), 0.001f);
            float maj2 = fmaxf(softplus_f(mx2), 0.001f);
            float mmax = fmaxf(fmaxf(maj0, maj1), maj2);

            float maj = (ch == 0) ? maj0 : ((ch == 1) ? maj1 : maj2);
            float t   = -log1pf(-ut) / maj + nears;

            if (t >= fars) {
                float den0 = __expf(-maj0*span)/(mmax+EPSF) + EPSF;
                float den1 = __expf(-maj1*span)/(mmax+EPSF) + EPSF;
                float den2 = __expf(-maj2*span)/(mmax+EPSF) + EPSF;
                float idm = 3.0f / (den0+den1+den2);
                float v0,v1,v2;
                env_logv(env_map, fmaf(dx,fars,ox), fmaf(dy,fars,oy), fmaf(dz,fars,oz), v0,v1,v2);
                rgb0 = den0*idm*__expf(v0);
                rgb1 = den1*idm*__expf(v1);
                rgb2 = den2*idm*__expf(v2);
                alive = false;
            } else {
                float tn  = t - nears;
                float imm = 1.0f / mmax;
                float tr0 = __expf(-maj0*tn) * imm;
                float tr1 = __expf(-maj1*tn) * imm;
                float tr2 = __expf(-maj2*tn) * imm;
                float i2m = 3.0f / (maj0*tr0 + maj1*tr1 + maj2*tr2);
                thr0 = tr0 * i2m;   // thr was 1
                thr1 = tr1 * i2m;
                thr2 = tr2 * i2m;
                ox = fmaf(dx, t, ox); oy = fmaf(dy, t, oy); oz = fmaf(dz, t, oz);

                // material MLP (DS-only loop; pre = P + t*Q)
                float st0=0.f, st1=0.f, st2=0.f;
                float dn0=0.f, dn1=0.f, dn2v=0.f;
                float rh0=0.f, rh1=0.f, rh2=0.f;
                const int j0 = half * 32;
                #pragma unroll 2
                for (int j = j0; j < j0 + 32; ++j) {
                    f32x4 q0 = sM0[j];
                    f32x4 q1 = sM1[j];
                    f32x4 q2 = sM2[j];
                    float pre = fmaf(t, q0.y, q0.x);
                    float f = tanh_fast(pre);
                    st0  = fmaf(f, q0.z, st0);
                    st1  = fmaf(f, q0.w, st1);
                    st2  = fmaf(f, q1.x, st2);
                    dn0  = fmaf(f, q1.y, dn0);
                    dn1  = fmaf(f, q1.z, dn1);
                    dn2v = fmaf(f, q1.w, dn2v);
                    rh0  = fmaf(f, q2.x, rh0);
                    rh1  = fmaf(f, q2.y, rh1);
                    rh2  = fmaf(f, q2.z, rh2);
                }
                st0  += __shfl_xor(st0, 1, 64);
                st1  += __shfl_xor(st1, 1, 64);
                st2  += __shfl_xor(st2, 1, 64);
                dn0  += __shfl_xor(dn0, 1, 64);
                dn1  += __shfl_xor(dn1, 1, 64);
                dn2v += __shfl_xor(dn2v, 1, 64);
                rh0  += __shfl_xor(rh0, 1, 64);
                rh1  += __shfl_xor(rh1, 1, 64);
                rh2  += __shfl_xor(rh2, 1, 64);

                float stch = (ch == 0) ? st0 : ((ch == 1) ? st1 : st2);
                float sp = fminf(softplus_f(stch) / maj, 1.0f);
                if (us < sp) {
                    float inr = 1.0f / (sqrtf(dn0*dn0 + dn1*dn1 + dn2v*dn2v) + EPSF);
                    dx = dn0*inr; dy = dn1*inr; dz = dn2v*inr;
                    float isp = 1.0f/(sp + EPSF);
                    thr0 *= isp * sigmoid_f(rh0);
                    thr1 *= isp * sigmoid_f(rh1);
                    thr2 *= isp * sigmoid_f(rh2);
                } else {
                    float iv = 1.0f/(1.0f - sp + EPSF);
                    thr0 *= iv; thr1 *= iv; thr2 *= iv;
                }
            }
        }
    }

    // ================= depth 1 (t = fars -> hit if delta>0) =================
    if (alive) {
        float a = dx*dx + dy*dy + dz*dz;
        float b = 2.0f*(dx*ox + dy*oy + dz*oz);
        float c = (ox*ox + oy*oy + oz*oz) - 1.0f;
        float delta = b*b - 4.0f*a*c;
        if (delta > 0.0f) {
            float sq    = sqrtf(delta);
            float nears = fmaxf((-b - sq) / (2.0f*a), 0.001f);
            float fars  = fmaxf((-b + sq) / (2.0f*a), 0.001f);
            float span  = fars - nears;

            float mx0, mx1, mx2;
            density_max3_half_d1(sPW, sW01, sW2, ox,oy,oz, dx,dy,dz, nears, span,
                                 j1A, j1B, kbase, mx0,mx1,mx2);
            mx0 = fmaxf(mx0, __shfl_xor(mx0, 1, 64));
            mx1 = fmaxf(mx1, __shfl_xor(mx1, 1, 64));
            mx2 = fmaxf(mx2, __shfl_xor(mx2, 1, 64));

            float maj0 = fmaxf(softplus_f(mx0), 0.001f);
            float maj1 = fmaxf(softplus_f(mx1), 0.001f);
            float maj2 = fmaxf(softplus_f(mx2), 0.001f);
            float mmax = fmaxf(fmaxf(maj0, maj1), maj2);

            float den0 = __expf(-maj0*span)/(mmax+EPSF) + EPSF;
            float den1 = __expf(-maj1*span)/(mmax+EPSF) + EPSF;
            float den2 = __expf(-maj2*span)/(mmax+EPSF) + EPSF;
            float idm = 3.0f / (den0+den1+den2);
            float v0,v1,v2;
            env_logv(env_map, fmaf(dx,fars,ox), fmaf(dy,fars,oy), fmaf(dz,fars,oz), v0,v1,v2);
            rgb0 += thr0 * den0*idm*__expf(v0);
            rgb1 += thr1 * den1*idm*__expf(v1);
            rgb2 += thr2 * den2*idm*__expf(v2);
        }
    }

    // ---- reduction: each sub-ray duplicated x2 -> sum/256 == mean/128 ----
    float r0 = rgb0, r1 = rgb1, r2 = rgb2;
    #pragma unroll
    for (int off = 32; off > 0; off >>= 1) {
        r0 += __shfl_down(r0, off, 64);
        r1 += __shfl_down(r1, off, 64);
        r2 += __shfl_down(r2, off, 64);
    }
    int wave = tid >> 6;
    if ((tid & 63) == 0) {
        sred[wave][0] = r0; sred[wave][1] = r1; sred[wave][2] = r2;
    }
    __syncthreads();
    if (tid == 0) {
        out[ray*3+0] = (sred[0][0]+sred[1][0]+sred[2][0]+sred[3][0]) * (1.0f/256.0f);
        out[ray*3+1] = (sred[0][1]+sred[1][1]+sred[2][1]+sred[3][1]) * (1.0f/256.0f);
        out[ray*3+2] = (sred[0][2]+sred[1][2]+sred[2][2]+sred[3][2]) * (1.0f/256.0f);
    }
}

extern "C" void kernel_launch(void* const* d_in, const int* in_sizes, int n_in,
                              void* d_out, int out_size, void* d_ws, size_t ws_size,
                              hipStream_t stream) {
    const float* rays_o    = (const float*)d_in[0];
    const float* rays_d    = (const float*)d_in[1];
    const float* env_map   = (const float*)d_in[2];
    const float* Wd1       = (const float*)d_in[3];
    const float* Wd2       = (const float*)d_in[4];
    const float* Wf1       = (const float*)d_in[5];
    const float* Ws        = (const float*)d_in[6];
    const float* Wdir      = (const float*)d_in[7];
    const float* Wrho      = (const float*)d_in[8];
    const float* jitter    = (const float*)d_in[9];
    const float* u_t       = (const float*)d_in[10];
    const float* u_scatter = (const float*)d_in[11];
    const int*   channel   = (const int*)d_in[12];
    float* out = (float*)d_out;

    render_kernel<<<dim3(NRAYS), dim3(256), 0, stream>>>(
        rays_o, rays_d, env_map, Wd1, Wd2, Wf1, Ws, Wdir, Wrho,
        jitter, u_t, u_scatter, channel, out);
}

// Round 11
// 168.538 us; speedup vs baseline: 1.2758x; 1.1640x over previous
//
#include <hip/hip_runtime.h>
#include <math.h>

#define NRAYS 2048
#define TOT   128
#define INDS  16
#define HID   64
#define EPSF  1e-8f
#define MTOT  (NRAYS*TOT)
#define NTAB  128

typedef float f32x2 __attribute__((ext_vector_type(2)));
typedef float f32x4 __attribute__((ext_vector_type(4)));

__device__ __forceinline__ float softplus_f(float x) {
    return fmaxf(x, 0.0f) + __logf(1.0f + __expf(-fabsf(x)));
}
__device__ __forceinline__ float sigmoid_f(float x) {
    return 1.0f / (1.0f + __expf(-x));
}
__device__ __forceinline__ float tanh_fast(float x) {
    float e2 = __expf(2.0f * x);
    return 1.0f - 2.0f / (e2 + 1.0f);
}
__device__ __forceinline__ f32x2 pkmax(f32x2 a, f32x2 b) {
    f32x2 r; r.x = fmaxf(a.x, b.x); r.y = fmaxf(a.y, b.y); return r;
}
__device__ __forceinline__ f32x2 pkfma(f32x2 a, f32x2 b, f32x2 c) {
    return __builtin_elementwise_fma(a, b, c);
}
__device__ __forceinline__ f32x4 fma4(f32x4 a, f32x4 b, f32x4 c) {
    return __builtin_elementwise_fma(a, b, c);
}

// z_k = fma(j_k, span/16, fma(span, k/15 - 1/32, nears))
#define CK(i) ((float)(i)*(1.0f/15.0f) - 0.03125f)

#define MAKE_Z(jA, jB, kbase, nears, span)                                    \
    float s16 = (span) * (1.0f/16.0f);                                        \
    f32x2 z01, z23, z45, z67;                                                 \
    z01.x = fmaf((jA).x, s16, fmaf(span, CK((kbase)+0), nears));              \
    z01.y = fmaf((jA).y, s16, fmaf(span, CK((kbase)+1), nears));              \
    z23.x = fmaf((jA).z, s16, fmaf(span, CK((kbase)+2), nears));              \
    z23.y = fmaf((jA).w, s16, fmaf(span, CK((kbase)+3), nears));              \
    z45.x = fmaf((jB).x, s16, fmaf(span, CK((kbase)+4), nears));              \
    z45.y = fmaf((jB).y, s16, fmaf(span, CK((kbase)+5), nears));              \
    z67.x = fmaf((jB).z, s16, fmaf(span, CK((kbase)+6), nears));              \
    z67.y = fmaf((jB).w, s16, fmaf(span, CK((kbase)+7), nears));

// ---- depth-1 density (per-sub-ray o,d): unchanged r10 path ----
#define DENSITY_J_BODY(A2, B2, W0, W1, W2v)                                   \
    {                                                                         \
        f32x2 g01 = pkfma(z01, (B2), (A2));                                   \
        f32x2 g23 = pkfma(z23, (B2), (A2));                                   \
        f32x2 g45 = pkfma(z45, (B2), (A2));                                   \
        f32x2 g67 = pkfma(z67, (B2), (A2));                                   \
        f32x2 h01, h23, h45, h67;                                             \
        h01.x = __builtin_amdgcn_sinf(g01.x); h01.y = __builtin_amdgcn_sinf(g01.y); \
        h23.x = __builtin_amdgcn_sinf(g23.x); h23.y = __builtin_amdgcn_sinf(g23.y); \
        h45.x = __builtin_amdgcn_sinf(g45.x); h45.y = __builtin_amdgcn_sinf(g45.y); \
        h67.x = __builtin_amdgcn_sinf(g67.x); h67.y = __builtin_amdgcn_sinf(g67.y); \
        a0_01 = pkfma(h01,(W0),a0_01); a0_23 = pkfma(h23,(W0),a0_23);         \
        a0_45 = pkfma(h45,(W0),a0_45); a0_67 = pkfma(h67,(W0),a0_67);         \
        a1_01 = pkfma(h01,(W1),a1_01); a1_23 = pkfma(h23,(W1),a1_23);         \
        a1_45 = pkfma(h45,(W1),a1_45); a1_67 = pkfma(h67,(W1),a1_67);         \
        a2_01 = pkfma(h01,(W2v),a2_01); a2_23 = pkfma(h23,(W2v),a2_23);       \
        a2_45 = pkfma(h45,(W2v),a2_45); a2_67 = pkfma(h67,(W2v),a2_67);       \
    }

__device__ __forceinline__ void density_max3_half_d1(
    const f32x4* __restrict__ sPW, const f32x4* __restrict__ sW01,
    const f32x2* __restrict__ sW2,
    float ox, float oy, float oz, float dx, float dy, float dz,
    float nears, float span, float4 jA, float4 jB, int kbase,
    float& mx0o, float& mx1o, float& mx2o)
{
    MAKE_Z(jA, jB, kbase, nears, span)
    f32x2 a0_01 = {0.f,0.f}, a0_23 = {0.f,0.f}, a0_45 = {0.f,0.f}, a0_67 = {0.f,0.f};
    f32x2 a1_01 = {0.f,0.f}, a1_23 = {0.f,0.f}, a1_45 = {0.f,0.f}, a1_67 = {0.f,0.f};
    f32x2 a2_01 = {0.f,0.f}, a2_23 = {0.f,0.f}, a2_45 = {0.f,0.f}, a2_67 = {0.f,0.f};
    #pragma unroll 2
    for (int j = 0; j < HID; ++j) {
        f32x4 pw  = sPW[j];
        f32x4 w01 = sW01[j];
        f32x2 w2  = sW2[j];
        float A = fmaf(ox, pw.x, fmaf(oy, pw.y, oz*pw.z));
        float B = fmaf(dx, pw.x, fmaf(dy, pw.y, dz*pw.z));
        f32x2 A2 = {A, A}, B2 = {B, B};
        f32x2 W0 = {w01.x, w01.y}, W1 = {w01.z, w01.w};
        DENSITY_J_BODY(A2, B2, W0, W1, w2)
    }
    f32x2 p0 = pkmax(pkmax(a0_01, a0_23), pkmax(a0_45, a0_67));
    f32x2 p1 = pkmax(pkmax(a1_01, a1_23), pkmax(a1_45, a1_67));
    f32x2 p2 = pkmax(pkmax(a2_01, a2_23), pkmax(a2_45, a2_67));
    mx0o = fmaxf(p0.x, p0.y);
    mx1o = fmaxf(p1.x, p1.y);
    mx2o = fmaxf(p2.x, p2.y);
}

__device__ __forceinline__ void env_logv(
    const float* __restrict__ env_map,
    float px, float py, float pz,
    float& v0, float& v1, float& v2)
{
    float theta = atan2f(px, -pz) * (1.0f/3.14159265358979323846f);
    float acv = (fabsf(py) <= 1.0f) ? acosf(py) : 0.0f;  // nan_to_num(arccos)
    float phi = 0.63661977236758134308f * acv - 1.0f;    // 2/pi
    float ixf = ((theta + 1.0f)*256.0f - 1.0f)*0.5f;
    float iyf = ((phi   + 1.0f)*128.0f - 1.0f)*0.5f;
    float x0f = floorf(ixf), y0f = floorf(iyf);
    float wx = ixf - x0f, wy = iyf - y0f;
    v0 = 0.f; v1 = 0.f; v2 = 0.f;
    auto tap = [&](float xc, float yc, float w) {
        if (xc >= 0.0f && xc < 256.0f && yc >= 0.0f && yc < 128.0f) {
            int xi = (int)xc, yi = (int)yc;
            const float* e = env_map + yi*256 + xi;
            v0 += w * e[0];
            v1 += w * e[128*256];
            v2 += w * e[2*128*256];
        }
    };
    tap(x0f,      y0f,      (1.0f-wx)*(1.0f-wy));
    tap(x0f+1.0f, y0f,      wx*(1.0f-wy));
    tap(x0f,      y0f+1.0f, (1.0f-wx)*wy);
    tap(x0f+1.0f, y0f+1.0f, wx*wy);
}

// 256 threads/block = 1 ray; lane pair (2s,2s+1) shares sub-ray s.
// NEW (r11): depth-0 density via a 128-point LDS table of
// F_c(z) = sum_j sin(A_j + z B_j) w2[j][c]  (block-uniform function of z,
// frequencies <= ~0.3 rev/unit-z -> lerp error ~7e-5, invisible vs the
// 0.175 threshold). Build: 64 sins/thread-pair ONCE vs 64 sins per sample
// (2048 samples/block). Depth-1 keeps the exact per-sub-ray path.
__global__ __launch_bounds__(256)
void render_kernel(const float* __restrict__ rays_o,
                   const float* __restrict__ rays_d,
                   const float* __restrict__ env_map,
                   const float* __restrict__ Wd1,
                   const float* __restrict__ Wd2,
                   const float* __restrict__ Wf1,
                   const float* __restrict__ Ws,
                   const float* __restrict__ Wdir,
                   const float* __restrict__ Wrho,
                   const float* __restrict__ jitter,
                   const float* __restrict__ u_t,
                   const float* __restrict__ u_scatter,
                   const int*   __restrict__ channel,
                   float* __restrict__ out)
{
    const int ray  = blockIdx.x;
    const int tid  = threadIdx.x;
    const int s    = tid >> 1;
    const int half = tid & 1;
    const int m    = ray * TOT + s;
    const int kbase = half * 8;

    __shared__ f32x4 sAB[HID];     // {A,A,B,B}
    __shared__ f32x4 sW01[HID];    // {w20,w20,w21,w21}
    __shared__ f32x2 sW2[HID];     // {w22,w22}
    __shared__ f32x4 sPW[HID];     // {pw1x,pw1y,pw1z,0}
    __shared__ f32x4 sM0[HID];     // {P, Q, ws0, ws1}
    __shared__ f32x4 sM1[HID];     // {ws2, wd0, wd1, wd2}
    __shared__ f32x4 sM2[HID];     // {wr0, wr1, wr2, 0}
    __shared__ f32x4 sTab[NTAB];   // {F0,F1,F2,0} density table
    __shared__ float sred[4][3];

    // ---- prefetch ALL per-thread globals up front ----
    const float4* j0p = (const float4*)(jitter + (size_t)m*INDS + kbase);
    const float4* j1p = (const float4*)(jitter + ((size_t)MTOT + m)*INDS + kbase);
    float4 j0A = j0p[0], j0B = j0p[1];
    float4 j1A = j1p[0], j1B = j1p[1];
    int   ch = channel[m];
    float ut = u_t[m];
    float us = u_scatter[m];

    float ox = rays_o[ray*3+0], oy = rays_o[ray*3+1], oz = rays_o[ray*3+2];
    float dx = rays_d[ray*3+0], dy = rays_d[ray*3+1], dz = rays_d[ray*3+2];

    // ---- per-block weight tables ----
    if (tid < HID) {
        const float INV2PI = 0.15915494309189535f;
        float w1x = Wd1[tid], w1y = Wd1[HID+tid], w1z = Wd1[2*HID+tid];
        float pw1x = w1x*INV2PI, pw1y = w1y*INV2PI, pw1z = w1z*INV2PI;
        float A = ox*pw1x + oy*pw1y + oz*pw1z;
        float B = dx*pw1x + dy*pw1y + dz*pw1z;
        float w20 = Wd2[3*tid], w21 = Wd2[3*tid+1], w22 = Wd2[3*tid+2];
        sAB[tid]  = (f32x4){A, A, B, B};
        sW01[tid] = (f32x4){w20, w20, w21, w21};
        sW2[tid]  = (f32x2){w22, w22};
        sPW[tid]  = (f32x4){pw1x, pw1y, pw1z, 0.0f};
        float f0 = Wf1[tid],       f1 = Wf1[HID+tid],   f2 = Wf1[2*HID+tid];
        float f3 = Wf1[3*HID+tid], f4 = Wf1[4*HID+tid], f5 = Wf1[5*HID+tid];
        float P = ox*f0 + oy*f1 + oz*f2 + dx*f3 + dy*f4 + dz*f5;
        float Q = dx*f0 + dy*f1 + dz*f2;
        sM0[tid] = (f32x4){P, Q, Ws[3*tid], Ws[3*tid+1]};
        sM1[tid] = (f32x4){Ws[3*tid+2], Wdir[3*tid], Wdir[3*tid+1], Wdir[3*tid+2]};
        sM2[tid] = (f32x4){Wrho[3*tid], Wrho[3*tid+1], Wrho[3*tid+2], 0.0f};
    }
    __syncthreads();

    // ---- block-uniform depth-0 geometry ----
    float a0g = dx*dx + dy*dy + dz*dz;
    float b0g = 2.0f*(dx*ox + dy*oy + dz*oz);
    float c0g = (ox*ox + oy*oy + oz*oz) - 1.0f;
    float delta0 = b0g*b0g - 4.0f*a0g*c0g;
    bool alive = (delta0 > 0.0f);   // block-uniform at depth 0

    float nears = 0.f, fars = 0.f, span = 0.f, ztab0 = 0.f, invh = 0.f;
    if (alive) {
        float sq = sqrtf(delta0);
        nears = fmaxf((-b0g - sq) / (2.0f*a0g), 0.001f);
        fars  = fmaxf((-b0g + sq) / (2.0f*a0g), 0.001f);
        span  = fars - nears;
        // table domain covers all jittered z: [nears - span/32, fars + span/32]
        ztab0 = fmaf(-span, 0.03125f, nears);
        float width = span * 1.0625f;
        float hstep = width * (1.0f/(NTAB-1));
        invh = (float)(NTAB-1) / width;
        // ---- build: thread pair (2p,2p+1) -> grid point p, j-halves ----
        int p = tid >> 1;
        float zp = fmaf((float)p, hstep, ztab0);
        float f0 = 0.f, f1 = 0.f, f2 = 0.f;
        const int jb = half * 32;
        #pragma unroll 4
        for (int j = jb; j < jb + 32; ++j) {
            f32x4 ab  = sAB[j];
            f32x4 w01 = sW01[j];
            f32x2 w2  = sW2[j];
            float hv = __builtin_amdgcn_sinf(fmaf(zp, ab.z, ab.x));
            f0 = fmaf(hv, w01.x, f0);
            f1 = fmaf(hv, w01.z, f1);
            f2 = fmaf(hv, w2.x, f2);
        }
        f0 += __shfl_xor(f0, 1, 64);
        f1 += __shfl_xor(f1, 1, 64);
        f2 += __shfl_xor(f2, 1, 64);
        if (half == 0) sTab[p] = (f32x4){f0, f1, f2, 0.0f};
    }
    __syncthreads();

    float thr0 = 1.f, thr1 = 1.f, thr2 = 1.f;
    float rgb0 = 0.f, rgb1 = 0.f, rgb2 = 0.f;

    // ================= depth 0 =================
    if (alive) {
        MAKE_Z(j0A, j0B, kbase, nears, span)
        float mx0 = -1e30f, mx1 = -1e30f, mx2 = -1e30f;
#define TAB_EVAL(zz)                                                          \
        {                                                                     \
            float x = (zz - ztab0) * invh;                                    \
            x = fminf(fmaxf(x, 0.0f), (float)(NTAB-1) - 1e-3f);               \
            int i = (int)x; float w = x - (float)i;                           \
            f32x4 Ta = sTab[i]; f32x4 Tb = sTab[i+1];                         \
            f32x4 wv = {w, w, w, w};                                          \
            f32x4 F = fma4(wv, Tb - Ta, Ta);                                  \
            mx0 = fmaxf(mx0, F.x); mx1 = fmaxf(mx1, F.y); mx2 = fmaxf(mx2, F.z); \
        }
        TAB_EVAL(z01.x) TAB_EVAL(z01.y) TAB_EVAL(z23.x) TAB_EVAL(z23.y)
        TAB_EVAL(z45.x) TAB_EVAL(z45.y) TAB_EVAL(z67.x) TAB_EVAL(z67.y)
#undef TAB_EVAL
        mx0 = fmaxf(mx0, __shfl_xor(mx0, 1, 64));
        mx1 = fmaxf(mx1, __shfl_xor(mx1, 1, 64));
        mx2 = fmaxf(mx2, __shfl_xor(mx2, 1, 64));

        float maj0 = fmaxf(softplus_f(mx0), 0.001f);
        float maj1 = fmaxf(softplus_f(mx1), 0.001f);
        float maj2 = fmaxf(softplus_f(mx2), 0.001f);
        float mmax = fmaxf(fmaxf(maj0, maj1), maj2);

        float maj = (ch == 0) ? maj0 : ((ch == 1) ? maj1 : maj2);
        float t   = -log1pf(-ut) / maj + nears;

        if (t >= fars) {
            float den0 = __expf(-maj0*span)/(mmax+EPSF) + EPSF;
            float den1 = __expf(-maj1*span)/(mmax+EPSF) + EPSF;
            float den2 = __expf(-maj2*span)/(mmax+EPSF) + EPSF;
            float idm = 3.0f / (den0+den1+den2);
            float v0,v1,v2;
            env_logv(env_map, fmaf(dx,fars,ox), fmaf(dy,fars,oy), fmaf(dz,fars,oz), v0,v1,v2);
            rgb0 = den0*idm*__expf(v0);
            rgb1 = den1*idm*__expf(v1);
            rgb2 = den2*idm*__expf(v2);
            alive = false;
        } else {
            float tn  = t - nears;
            float imm = 1.0f / mmax;
            float tr0 = __expf(-maj0*tn) * imm;
            float tr1 = __expf(-maj1*tn) * imm;
            float tr2 = __expf(-maj2*tn) * imm;
            float i2m = 3.0f / (maj0*tr0 + maj1*tr1 + maj2*tr2);
            thr0 = tr0 * i2m;   // thr was 1
            thr1 = tr1 * i2m;
            thr2 = tr2 * i2m;
            ox = fmaf(dx, t, ox); oy = fmaf(dy, t, oy); oz = fmaf(dz, t, oz);

            // material MLP (DS-only loop; pre = P + t*Q)
            float st0=0.f, st1=0.f, st2=0.f;
            float dn0=0.f, dn1=0.f, dn2v=0.f;
            float rh0=0.f, rh1=0.f, rh2=0.f;
            const int j0 = half * 32;
            #pragma unroll 2
            for (int j = j0; j < j0 + 32; ++j) {
                f32x4 q0 = sM0[j];
                f32x4 q1 = sM1[j];
                f32x4 q2 = sM2[j];
                float pre = fmaf(t, q0.y, q0.x);
                float f = tanh_fast(pre);
                st0  = fmaf(f, q0.z, st0);
                st1  = fmaf(f, q0.w, st1);
                st2  = fmaf(f, q1.x, st2);
                dn0  = fmaf(f, q1.y, dn0);
                dn1  = fmaf(f, q1.z, dn1);
                dn2v = fmaf(f, q1.w, dn2v);
                rh0  = fmaf(f, q2.x, rh0);
                rh1  = fmaf(f, q2.y, rh1);
                rh2  = fmaf(f, q2.z, rh2);
            }
            st0  += __shfl_xor(st0, 1, 64);
            st1  += __shfl_xor(st1, 1, 64);
            st2  += __shfl_xor(st2, 1, 64);
            dn0  += __shfl_xor(dn0, 1, 64);
            dn1  += __shfl_xor(dn1, 1, 64);
            dn2v += __shfl_xor(dn2v, 1, 64);
            rh0  += __shfl_xor(rh0, 1, 64);
            rh1  += __shfl_xor(rh1, 1, 64);
            rh2  += __shfl_xor(rh2, 1, 64);

            float stch = (ch == 0) ? st0 : ((ch == 1) ? st1 : st2);
            float sp = fminf(softplus_f(stch) / maj, 1.0f);
            if (us < sp) {
                float inr = 1.0f / (sqrtf(dn0*dn0 + dn1*dn1 + dn2v*dn2v) + EPSF);
                dx = dn0*inr; dy = dn1*inr; dz = dn2v*inr;
                float isp = 1.0f/(sp + EPSF);
                thr0 *= isp * sigmoid_f(rh0);
                thr1 *= isp * sigmoid_f(rh1);
                thr2 *= isp * sigmoid_f(rh2);
            } else {
                float iv = 1.0f/(1.0f - sp + EPSF);
                thr0 *= iv; thr1 *= iv; thr2 *= iv;
            }
        }
    }

    // ================= depth 1 (t = fars -> hit if delta>0) =================
    if (alive) {
        float a = dx*dx + dy*dy + dz*dz;
        float b = 2.0f*(dx*ox + dy*oy + dz*oz);
        float c = (ox*ox + oy*oy + oz*oz) - 1.0f;
        float delta = b*b - 4.0f*a*c;
        if (delta > 0.0f) {
            float sq     = sqrtf(delta);
            float nears1 = fmaxf((-b - sq) / (2.0f*a), 0.001f);
            float fars1  = fmaxf((-b + sq) / (2.0f*a), 0.001f);
            float span1  = fars1 - nears1;

            float mx0, mx1, mx2;
            density_max3_half_d1(sPW, sW01, sW2, ox,oy,oz, dx,dy,dz, nears1, span1,
                                 j1A, j1B, kbase, mx0,mx1,mx2);
            mx0 = fmaxf(mx0, __shfl_xor(mx0, 1, 64));
            mx1 = fmaxf(mx1, __shfl_xor(mx1, 1, 64));
            mx2 = fmaxf(mx2, __shfl_xor(mx2, 1, 64));

            float maj0 = fmaxf(softplus_f(mx0), 0.001f);
            float maj1 = fmaxf(softplus_f(mx1), 0.001f);
            float maj2 = fmaxf(softplus_f(mx2), 0.001f);
            float mmax = fmaxf(fmaxf(maj0, maj1), maj2);

            float den0 = __expf(-maj0*span1)/(mmax+EPSF) + EPSF;
            float den1 = __expf(-maj1*span1)/(mmax+EPSF) + EPSF;
            float den2 = __expf(-maj2*span1)/(mmax+EPSF) + EPSF;
            float idm = 3.0f / (den0+den1+den2);
            float v0,v1,v2;
            env_logv(env_map, fmaf(dx,fars1,ox), fmaf(dy,fars1,oy), fmaf(dz,fars1,oz), v0,v1,v2);
            rgb0 += thr0 * den0*idm*__expf(v0);
            rgb1 += thr1 * den1*idm*__expf(v1);
            rgb2 += thr2 * den2*idm*__expf(v2);
        }
    }

    // ---- reduction: each sub-ray duplicated x2 -> sum/256 == mean/128 ----
    float r0 = rgb0, r1 = rgb1, r2 = rgb2;
    #pragma unroll
    for (int off = 32; off > 0; off >>= 1) {
        r0 += __shfl_down(r0, off, 64);
        r1 += __shfl_down(r1, off, 64);
        r2 += __shfl_down(r2, off, 64);
    }
    int wave = tid >> 6;
    if ((tid & 63) == 0) {
        sred[wave][0] = r0; sred[wave][1] = r1; sred[wave][2] = r2;
    }
    __syncthreads();
    if (tid == 0) {
        out[ray*3+0] = (sred[0][0]+sred[1][0]+sred[2][0]+sred[3][0]) * (1.0f/256.0f);
        out[ray*3+1] = (sred[0][1]+sred[1][1]+sred[2][1]+sred[3][1]) * (1.0f/256.0f);
        out[ray*3+2] = (sred[0][2]+sred[1][2]+sred[2][2]+sred[3][2]) * (1.0f/256.0f);
    }
}

extern "C" void kernel_launch(void* const* d_in, const int* in_sizes, int n_in,
                              void* d_out, int out_size, void* d_ws, size_t ws_size,
                              hipStream_t stream) {
    const float* rays_o    = (const float*)d_in[0];
    const float* rays_d    = (const float*)d_in[1];
    const float* env_map   = (const float*)d_in[2];
    const float* Wd1       = (const float*)d_in[3];
    const float* Wd2       = (const float*)d_in[4];
    const float* Wf1       = (const float*)d_in[5];
    const float* Ws        = (const float*)d_in[6];
    const float* Wdir      = (const float*)d_in[7];
    const float* Wrho      = (const float*)d_in[8];
    const float* jitter    = (const float*)d_in[9];
    const float* u_t       = (const float*)d_in[10];
    const float* u_scatter = (const float*)d_in[11];
    const int*   channel   = (const int*)d_in[12];
    float* out = (float*)d_out;

    render_kernel<<<dim3(NRAYS), dim3(256), 0, stream>>>(
        rays_o, rays_d, env_map, Wd1, Wd2, Wf1, Ws, Wdir, Wrho,
        jitter, u_t, u_scatter, channel, out);
}

// Round 12
// 168.060 us; speedup vs baseline: 1.2795x; 1.0028x over previous
//
#include <hip/hip_runtime.h>
#include <math.h>

#define NRAYS 2048
#define TOT   128
#define INDS  16
#define HID   64
#define EPSF  1e-8f
#define MTOT  (NRAYS*TOT)
#define NTAB  128

typedef float f32x2 __attribute__((ext_vector_type(2)));
typedef float f32x4 __attribute__((ext_vector_type(4)));

__device__ __forceinline__ float softplus_f(float x) {
    return fmaxf(x, 0.0f) + __logf(1.0f + __expf(-fabsf(x)));
}
__device__ __forceinline__ float sigmoid_f(float x) {
    return 1.0f / (1.0f + __expf(-x));
}
__device__ __forceinline__ float tanh_fast(float x) {
    float e2 = __expf(2.0f * x);
    return 1.0f - 2.0f / (e2 + 1.0f);
}
__device__ __forceinline__ f32x2 pkmax(f32x2 a, f32x2 b) {
    f32x2 r; r.x = fmaxf(a.x, b.x); r.y = fmaxf(a.y, b.y); return r;
}
__device__ __forceinline__ f32x2 pkfma(f32x2 a, f32x2 b, f32x2 c) {
    return __builtin_elementwise_fma(a, b, c);
}
__device__ __forceinline__ f32x4 fma4(f32x4 a, f32x4 b, f32x4 c) {
    return __builtin_elementwise_fma(a, b, c);
}

// z_k = fma(j_k, span/16, fma(span, k/15 - 1/32, nears))
#define CK(i) ((float)(i)*(1.0f/15.0f) - 0.03125f)

#define MAKE_Z(jA, jB, kbase, nears, span)                                    \
    float s16 = (span) * (1.0f/16.0f);                                        \
    f32x2 z01, z23, z45, z67;                                                 \
    z01.x = fmaf((jA).x, s16, fmaf(span, CK((kbase)+0), nears));              \
    z01.y = fmaf((jA).y, s16, fmaf(span, CK((kbase)+1), nears));              \
    z23.x = fmaf((jA).z, s16, fmaf(span, CK((kbase)+2), nears));              \
    z23.y = fmaf((jA).w, s16, fmaf(span, CK((kbase)+3), nears));              \
    z45.x = fmaf((jB).x, s16, fmaf(span, CK((kbase)+4), nears));              \
    z45.y = fmaf((jB).y, s16, fmaf(span, CK((kbase)+5), nears));              \
    z67.x = fmaf((jB).z, s16, fmaf(span, CK((kbase)+6), nears));              \
    z67.y = fmaf((jB).w, s16, fmaf(span, CK((kbase)+7), nears));

// lerp the block density table at absolute coordinate zz
#define TAB_EVAL(zz, mx0, mx1, mx2)                                           \
    {                                                                         \
        float x = ((zz) - ztab0) * invh;                                      \
        x = fminf(fmaxf(x, 0.0f), (float)(NTAB-1) - 1e-3f);                   \
        int i = (int)x; float w = x - (float)i;                               \
        f32x4 Ta = sTab[i]; f32x4 Tb = sTab[i+1];                             \
        f32x4 wv = {w, w, w, w};                                              \
        f32x4 F = fma4(wv, Tb - Ta, Ta);                                      \
        mx0 = fmaxf(mx0, F.x); mx1 = fmaxf(mx1, F.y); mx2 = fmaxf(mx2, F.z);  \
    }

// ---- exact per-sub-ray density (scattered rays at depth 1) ----
#define DENSITY_J_BODY(A2, B2, W0, W1, W2v)                                   \
    {                                                                         \
        f32x2 g01 = pkfma(z01, (B2), (A2));                                   \
        f32x2 g23 = pkfma(z23, (B2), (A2));                                   \
        f32x2 g45 = pkfma(z45, (B2), (A2));                                   \
        f32x2 g67 = pkfma(z67, (B2), (A2));                                   \
        f32x2 h01, h23, h45, h67;                                             \
        h01.x = __builtin_amdgcn_sinf(g01.x); h01.y = __builtin_amdgcn_sinf(g01.y); \
        h23.x = __builtin_amdgcn_sinf(g23.x); h23.y = __builtin_amdgcn_sinf(g23.y); \
        h45.x = __builtin_amdgcn_sinf(g45.x); h45.y = __builtin_amdgcn_sinf(g45.y); \
        h67.x = __builtin_amdgcn_sinf(g67.x); h67.y = __builtin_amdgcn_sinf(g67.y); \
        a0_01 = pkfma(h01,(W0),a0_01); a0_23 = pkfma(h23,(W0),a0_23);         \
        a0_45 = pkfma(h45,(W0),a0_45); a0_67 = pkfma(h67,(W0),a0_67);         \
        a1_01 = pkfma(h01,(W1),a1_01); a1_23 = pkfma(h23,(W1),a1_23);         \
        a1_45 = pkfma(h45,(W1),a1_45); a1_67 = pkfma(h67,(W1),a1_67);         \
        a2_01 = pkfma(h01,(W2v),a2_01); a2_23 = pkfma(h23,(W2v),a2_23);       \
        a2_45 = pkfma(h45,(W2v),a2_45); a2_67 = pkfma(h67,(W2v),a2_67);       \
    }

__device__ __forceinline__ void density_max3_half_d1(
    const f32x4* __restrict__ sPW, const f32x4* __restrict__ sW01,
    const f32x2* __restrict__ sW2,
    float ox, float oy, float oz, float dx, float dy, float dz,
    float nears, float span, float4 jA, float4 jB, int kbase,
    float& mx0o, float& mx1o, float& mx2o)
{
    MAKE_Z(jA, jB, kbase, nears, span)
    f32x2 a0_01 = {0.f,0.f}, a0_23 = {0.f,0.f}, a0_45 = {0.f,0.f}, a0_67 = {0.f,0.f};
    f32x2 a1_01 = {0.f,0.f}, a1_23 = {0.f,0.f}, a1_45 = {0.f,0.f}, a1_67 = {0.f,0.f};
    f32x2 a2_01 = {0.f,0.f}, a2_23 = {0.f,0.f}, a2_45 = {0.f,0.f}, a2_67 = {0.f,0.f};
    #pragma unroll 2
    for (int j = 0; j < HID; ++j) {
        f32x4 pw  = sPW[j];
        f32x4 w01 = sW01[j];
        f32x2 w2  = sW2[j];
        float A = fmaf(ox, pw.x, fmaf(oy, pw.y, oz*pw.z));
        float B = fmaf(dx, pw.x, fmaf(dy, pw.y, dz*pw.z));
        f32x2 A2 = {A, A}, B2 = {B, B};
        f32x2 W0 = {w01.x, w01.y}, W1 = {w01.z, w01.w};
        DENSITY_J_BODY(A2, B2, W0, W1, w2)
    }
    f32x2 p0 = pkmax(pkmax(a0_01, a0_23), pkmax(a0_45, a0_67));
    f32x2 p1 = pkmax(pkmax(a1_01, a1_23), pkmax(a1_45, a1_67));
    f32x2 p2 = pkmax(pkmax(a2_01, a2_23), pkmax(a2_45, a2_67));
    mx0o = fmaxf(p0.x, p0.y);
    mx1o = fmaxf(p1.x, p1.y);
    mx2o = fmaxf(p2.x, p2.y);
}

__device__ __forceinline__ void env_logv(
    const float* __restrict__ env_map,
    float px, float py, float pz,
    float& v0, float& v1, float& v2)
{
    float theta = atan2f(px, -pz) * (1.0f/3.14159265358979323846f);
    float acv = (fabsf(py) <= 1.0f) ? acosf(py) : 0.0f;  // nan_to_num(arccos)
    float phi = 0.63661977236758134308f * acv - 1.0f;    // 2/pi
    float ixf = ((theta + 1.0f)*256.0f - 1.0f)*0.5f;
    float iyf = ((phi   + 1.0f)*128.0f - 1.0f)*0.5f;
    float x0f = floorf(ixf), y0f = floorf(iyf);
    float wx = ixf - x0f, wy = iyf - y0f;
    v0 = 0.f; v1 = 0.f; v2 = 0.f;
    auto tap = [&](float xc, float yc, float w) {
        if (xc >= 0.0f && xc < 256.0f && yc >= 0.0f && yc < 128.0f) {
            int xi = (int)xc, yi = (int)yc;
            const float* e = env_map + yi*256 + xi;
            v0 += w * e[0];
            v1 += w * e[128*256];
            v2 += w * e[2*128*256];
        }
    };
    tap(x0f,      y0f,      (1.0f-wx)*(1.0f-wy));
    tap(x0f+1.0f, y0f,      wx*(1.0f-wy));
    tap(x0f,      y0f+1.0f, (1.0f-wx)*wy);
    tap(x0f+1.0f, y0f+1.0f, wx*wy);
}

// 256 threads/block = 1 ray; lane pair (2s,2s+1) shares sub-ray s.
// r11: depth-0 density from 128-pt LDS table of block-uniform F(z).
// NEW (r12):
//  * non-scattered depth-1 rays have d == d0 -> their density is F(t+z):
//    reuse the SAME table (domain verified: t+fars1 == fars0).
//  * their env exit == o0 + fars0*d0 == block-uniform -> exp(env) computed
//    once per block (also reused by the depth-0 hit branch).
//  * scattered rays are COMPACTED into an LDS pool (atomicAdd slots) and
//    only ceil(2*scnt/64) waves run the exact 512-sin path; tail waves
//    skip via execz. Expected scatter fraction ~0.5.
__global__ __launch_bounds__(256)
void render_kernel(const float* __restrict__ rays_o,
                   const float* __restrict__ rays_d,
                   const float* __restrict__ env_map,
                   const float* __restrict__ Wd1,
                   const float* __restrict__ Wd2,
                   const float* __restrict__ Wf1,
                   const float* __restrict__ Ws,
                   const float* __restrict__ Wdir,
                   const float* __restrict__ Wrho,
                   const float* __restrict__ jitter,
                   const float* __restrict__ u_t,
                   const float* __restrict__ u_scatter,
                   const int*   __restrict__ channel,
                   float* __restrict__ out)
{
    const int ray  = blockIdx.x;
    const int tid  = threadIdx.x;
    const int s    = tid >> 1;
    const int half = tid & 1;
    const int m    = ray * TOT + s;
    const int kbase = half * 8;

    __shared__ f32x4 sAB[HID];     // {A,A,B,B}
    __shared__ f32x4 sW01[HID];    // {w20,w20,w21,w21}
    __shared__ f32x2 sW2[HID];     // {w22,w22}
    __shared__ f32x4 sPW[HID];     // {pw1x,pw1y,pw1z,0}
    __shared__ f32x4 sM0[HID];     // {P, Q, ws0, ws1}
    __shared__ f32x4 sM1[HID];     // {ws2, wd0, wd1, wd2}
    __shared__ f32x4 sM2[HID];     // {wr0, wr1, wr2, 0}
    __shared__ f32x4 sTab[NTAB];   // {F0,F1,F2,0}
    __shared__ f32x4 sP0[TOT];     // pool: {ox,oy,oz,dx}
    __shared__ f32x4 sP1[TOT];     // pool: {dy,dz,thr0,thr1}
    __shared__ f32x2 sP2[TOT];     // pool: {thr2, (float)m}
    __shared__ float sEnvE[3];     // exp(env) at block-uniform exit point
    __shared__ int   sCnt;
    __shared__ float sred[4][3];

    // ---- prefetch per-thread globals ----
    const float4* j0p = (const float4*)(jitter + (size_t)m*INDS + kbase);
    const float4* j1p = (const float4*)(jitter + ((size_t)MTOT + m)*INDS + kbase);
    float4 j0A = j0p[0], j0B = j0p[1];
    float4 j1A = j1p[0], j1B = j1p[1];
    int   ch = channel[m];
    float ut = u_t[m];
    float us = u_scatter[m];

    float ox = rays_o[ray*3+0], oy = rays_o[ray*3+1], oz = rays_o[ray*3+2];
    float dx = rays_d[ray*3+0], dy = rays_d[ray*3+1], dz = rays_d[ray*3+2];

    if (tid == 0) sCnt = 0;
    // ---- per-block weight tables ----
    if (tid < HID) {
        const float INV2PI = 0.15915494309189535f;
        float w1x = Wd1[tid], w1y = Wd1[HID+tid], w1z = Wd1[2*HID+tid];
        float pw1x = w1x*INV2PI, pw1y = w1y*INV2PI, pw1z = w1z*INV2PI;
        float A = ox*pw1x + oy*pw1y + oz*pw1z;
        float B = dx*pw1x + dy*pw1y + dz*pw1z;
        float w20 = Wd2[3*tid], w21 = Wd2[3*tid+1], w22 = Wd2[3*tid+2];
        sAB[tid]  = (f32x4){A, A, B, B};
        sW01[tid] = (f32x4){w20, w20, w21, w21};
        sW2[tid]  = (f32x2){w22, w22};
        sPW[tid]  = (f32x4){pw1x, pw1y, pw1z, 0.0f};
        float f0 = Wf1[tid],       f1 = Wf1[HID+tid],   f2 = Wf1[2*HID+tid];
        float f3 = Wf1[3*HID+tid], f4 = Wf1[4*HID+tid], f5 = Wf1[5*HID+tid];
        float P = ox*f0 + oy*f1 + oz*f2 + dx*f3 + dy*f4 + dz*f5;
        float Q = dx*f0 + dy*f1 + dz*f2;
        sM0[tid] = (f32x4){P, Q, Ws[3*tid], Ws[3*tid+1]};
        sM1[tid] = (f32x4){Ws[3*tid+2], Wdir[3*tid], Wdir[3*tid+1], Wdir[3*tid+2]};
        sM2[tid] = (f32x4){Wrho[3*tid], Wrho[3*tid+1], Wrho[3*tid+2], 0.0f};
    }
    __syncthreads();

    // ---- block-uniform depth-0 geometry + density table + env ----
    float a0g = dx*dx + dy*dy + dz*dz;
    float b0g = 2.0f*(dx*ox + dy*oy + dz*oz);
    float c0g = (ox*ox + oy*oy + oz*oz) - 1.0f;
    float delta0 = b0g*b0g - 4.0f*a0g*c0g;
    bool alive = (delta0 > 0.0f);   // block-uniform

    float nears = 0.f, fars = 0.f, span = 0.f, ztab0 = 0.f, invh = 0.f;
    if (alive) {
        float sq = sqrtf(delta0);
        nears = fmaxf((-b0g - sq) / (2.0f*a0g), 0.001f);
        fars  = fmaxf((-b0g + sq) / (2.0f*a0g), 0.001f);
        span  = fars - nears;
        ztab0 = fmaf(-span, 0.03125f, nears);
        float width = span * 1.0625f;
        float hstep = width * (1.0f/(NTAB-1));
        invh = (float)(NTAB-1) / width;
        int p = tid >> 1;
        float zp = fmaf((float)p, hstep, ztab0);
        float f0 = 0.f, f1 = 0.f, f2 = 0.f;
        const int jb = half * 32;
        #pragma unroll 4
        for (int j = jb; j < jb + 32; ++j) {
            f32x4 ab  = sAB[j];
            f32x4 w01 = sW01[j];
            f32x2 w2  = sW2[j];
            float hv = __builtin_amdgcn_sinf(fmaf(zp, ab.z, ab.x));
            f0 = fmaf(hv, w01.x, f0);
            f1 = fmaf(hv, w01.z, f1);
            f2 = fmaf(hv, w2.x, f2);
        }
        f0 += __shfl_xor(f0, 1, 64);
        f1 += __shfl_xor(f1, 1, 64);
        f2 += __shfl_xor(f2, 1, 64);
        if (half == 0) sTab[p] = (f32x4){f0, f1, f2, 0.0f};
        if (tid == 0) {
            float v0,v1,v2;
            env_logv(env_map, fmaf(dx,fars,ox), fmaf(dy,fars,oy), fmaf(dz,fars,oz),
                     v0,v1,v2);
            sEnvE[0] = __expf(v0); sEnvE[1] = __expf(v1); sEnvE[2] = __expf(v2);
        }
    }
    __syncthreads();

    float thr0 = 1.f, thr1 = 1.f, thr2 = 1.f;
    float rgb0 = 0.f, rgb1 = 0.f, rgb2 = 0.f;
    bool  tab_d1 = false;
    float tadv = 0.f;

    // ================= depth 0 =================
    if (alive) {
        MAKE_Z(j0A, j0B, kbase, nears, span)
        float mx0 = -1e30f, mx1 = -1e30f, mx2 = -1e30f;
        TAB_EVAL(z01.x, mx0,mx1,mx2) TAB_EVAL(z01.y, mx0,mx1,mx2)
        TAB_EVAL(z23.x, mx0,mx1,mx2) TAB_EVAL(z23.y, mx0,mx1,mx2)
        TAB_EVAL(z45.x, mx0,mx1,mx2) TAB_EVAL(z45.y, mx0,mx1,mx2)
        TAB_EVAL(z67.x, mx0,mx1,mx2) TAB_EVAL(z67.y, mx0,mx1,mx2)
        mx0 = fmaxf(mx0, __shfl_xor(mx0, 1, 64));
        mx1 = fmaxf(mx1, __shfl_xor(mx1, 1, 64));
        mx2 = fmaxf(mx2, __shfl_xor(mx2, 1, 64));

        float maj0 = fmaxf(softplus_f(mx0), 0.001f);
        float maj1 = fmaxf(softplus_f(mx1), 0.001f);
        float maj2 = fmaxf(softplus_f(mx2), 0.001f);
        float mmax = fmaxf(fmaxf(maj0, maj1), maj2);

        float maj = (ch == 0) ? maj0 : ((ch == 1) ? maj1 : maj2);
        float t   = -log1pf(-ut) / maj + nears;

        if (t >= fars) {
            float den0 = __expf(-maj0*span)/(mmax+EPSF) + EPSF;
            float den1 = __expf(-maj1*span)/(mmax+EPSF) + EPSF;
            float den2 = __expf(-maj2*span)/(mmax+EPSF) + EPSF;
            float idm = 3.0f / (den0+den1+den2);
            rgb0 = den0*idm*sEnvE[0];
            rgb1 = den1*idm*sEnvE[1];
            rgb2 = den2*idm*sEnvE[2];
        } else {
            float tn  = t - nears;
            float imm = 1.0f / mmax;
            float tr0 = __expf(-maj0*tn) * imm;
            float tr1 = __expf(-maj1*tn) * imm;
            float tr2 = __expf(-maj2*tn) * imm;
            float i2m = 3.0f / (maj0*tr0 + maj1*tr1 + maj2*tr2);
            thr0 = tr0 * i2m;   // thr was 1
            thr1 = tr1 * i2m;
            thr2 = tr2 * i2m;
            ox = fmaf(dx, t, ox); oy = fmaf(dy, t, oy); oz = fmaf(dz, t, oz);

            // material MLP (DS-only; pre = P + t*Q)
            float st0=0.f, st1=0.f, st2=0.f;
            float dn0=0.f, dn1=0.f, dn2v=0.f;
            float rh0=0.f, rh1=0.f, rh2=0.f;
            const int j0 = half * 32;
            #pragma unroll 2
            for (int j = j0; j < j0 + 32; ++j) {
                f32x4 q0 = sM0[j];
                f32x4 q1 = sM1[j];
                f32x4 q2 = sM2[j];
                float pre = fmaf(t, q0.y, q0.x);
                float f = tanh_fast(pre);
                st0  = fmaf(f, q0.z, st0);
                st1  = fmaf(f, q0.w, st1);
                st2  = fmaf(f, q1.x, st2);
                dn0  = fmaf(f, q1.y, dn0);
                dn1  = fmaf(f, q1.z, dn1);
                dn2v = fmaf(f, q1.w, dn2v);
                rh0  = fmaf(f, q2.x, rh0);
                rh1  = fmaf(f, q2.y, rh1);
                rh2  = fmaf(f, q2.z, rh2);
            }
            st0  += __shfl_xor(st0, 1, 64);
            st1  += __shfl_xor(st1, 1, 64);
            st2  += __shfl_xor(st2, 1, 64);
            dn0  += __shfl_xor(dn0, 1, 64);
            dn1  += __shfl_xor(dn1, 1, 64);
            dn2v += __shfl_xor(dn2v, 1, 64);
            rh0  += __shfl_xor(rh0, 1, 64);
            rh1  += __shfl_xor(rh1, 1, 64);
            rh2  += __shfl_xor(rh2, 1, 64);

            float stch = (ch == 0) ? st0 : ((ch == 1) ? st1 : st2);
            float sp = fminf(softplus_f(stch) / maj, 1.0f);
            if (us < sp) {
                // scattered: push to pool for the compacted exact pass
                float inr = 1.0f / (sqrtf(dn0*dn0 + dn1*dn1 + dn2v*dn2v) + EPSF);
                float ndx = dn0*inr, ndy = dn1*inr, ndz = dn2v*inr;
                float isp = 1.0f/(sp + EPSF);
                float t0 = thr0 * isp * sigmoid_f(rh0);
                float t1 = thr1 * isp * sigmoid_f(rh1);
                float t2 = thr2 * isp * sigmoid_f(rh2);
                if (half == 0) {
                    int sl = atomicAdd(&sCnt, 1);
                    sP0[sl] = (f32x4){ox, oy, oz, ndx};
                    sP1[sl] = (f32x4){ndy, ndz, t0, t1};
                    sP2[sl] = (f32x2){t2, (float)m};
                }
            } else {
                float iv = 1.0f/(1.0f - sp + EPSF);
                thr0 *= iv; thr1 *= iv; thr2 *= iv;
                tab_d1 = true;
                tadv = t;
            }
        }
    }
    __syncthreads();
    int npool = sCnt;

    // ===== depth 1, non-scattered: d == d0 -> density = F(tadv + z) =====
    if (tab_d1) {
        float a1 = dx*dx + dy*dy + dz*dz;
        float b1 = 2.0f*(dx*ox + dy*oy + dz*oz);
        float c1 = (ox*ox + oy*oy + oz*oz) - 1.0f;
        float delta1 = b1*b1 - 4.0f*a1*c1;
        if (delta1 > 0.0f) {
            float sq1    = sqrtf(delta1);
            float nears1 = fmaxf((-b1 - sq1) / (2.0f*a1), 0.001f);
            float fars1  = fmaxf((-b1 + sq1) / (2.0f*a1), 0.001f);
            float span1  = fars1 - nears1;
            MAKE_Z(j1A, j1B, kbase, nears1, span1)
            float mx0 = -1e30f, mx1 = -1e30f, mx2 = -1e30f;
            TAB_EVAL(tadv + z01.x, mx0,mx1,mx2) TAB_EVAL(tadv + z01.y, mx0,mx1,mx2)
            TAB_EVAL(tadv + z23.x, mx0,mx1,mx2) TAB_EVAL(tadv + z23.y, mx0,mx1,mx2)
            TAB_EVAL(tadv + z45.x, mx0,mx1,mx2) TAB_EVAL(tadv + z45.y, mx0,mx1,mx2)
            TAB_EVAL(tadv + z67.x, mx0,mx1,mx2) TAB_EVAL(tadv + z67.y, mx0,mx1,mx2)
            mx0 = fmaxf(mx0, __shfl_xor(mx0, 1, 64));
            mx1 = fmaxf(mx1, __shfl_xor(mx1, 1, 64));
            mx2 = fmaxf(mx2, __shfl_xor(mx2, 1, 64));

            float maj0 = fmaxf(softplus_f(mx0), 0.001f);
            float maj1 = fmaxf(softplus_f(mx1), 0.001f);
            float maj2 = fmaxf(softplus_f(mx2), 0.001f);
            float mmax = fmaxf(fmaxf(maj0, maj1), maj2);

            float den0 = __expf(-maj0*span1)/(mmax+EPSF) + EPSF;
            float den1 = __expf(-maj1*span1)/(mmax+EPSF) + EPSF;
            float den2 = __expf(-maj2*span1)/(mmax+EPSF) + EPSF;
            float idm = 3.0f / (den0+den1+den2);
            // exit point == o0 + fars0*d0 (block-uniform)
            rgb0 += thr0 * den0*idm*sEnvE[0];
            rgb1 += thr1 * den1*idm*sEnvE[1];
            rgb2 += thr2 * den2*idm*sEnvE[2];
        }
    }

    // ===== depth 1, scattered: compacted exact pass =====
    {
        int q = tid >> 1;
        if (q < npool) {
            f32x4 p0 = sP0[q];
            f32x4 p1 = sP1[q];
            f32x2 p2 = sP2[q];
            float pox = p0.x, poy = p0.y, poz = p0.z;
            float pdx = p0.w, pdy = p1.x, pdz = p1.y;
            float pt0 = p1.z, pt1 = p1.w, pt2 = p2.x;
            int   mm  = (int)p2.y;
            const float4* jp = (const float4*)(jitter + ((size_t)MTOT + mm)*INDS + kbase);
            float4 jA = jp[0], jB = jp[1];   // L2-warm (fetched at entry)

            float a1 = pdx*pdx + pdy*pdy + pdz*pdz;
            float b1 = 2.0f*(pdx*pox + pdy*poy + pdz*poz);
            float c1 = (pox*pox + poy*poy + poz*poz) - 1.0f;
            float delta1 = b1*b1 - 4.0f*a1*c1;
            if (delta1 > 0.0f) {
                float sq1    = sqrtf(delta1);
                float nears1 = fmaxf((-b1 - sq1) / (2.0f*a1), 0.001f);
                float fars1  = fmaxf((-b1 + sq1) / (2.0f*a1), 0.001f);
                float span1  = fars1 - nears1;

                float mx0, mx1, mx2;
                density_max3_half_d1(sPW, sW01, sW2, pox,poy,poz, pdx,pdy,pdz,
                                     nears1, span1, jA, jB, kbase, mx0,mx1,mx2);
                mx0 = fmaxf(mx0, __shfl_xor(mx0, 1, 64));
                mx1 = fmaxf(mx1, __shfl_xor(mx1, 1, 64));
                mx2 = fmaxf(mx2, __shfl_xor(mx2, 1, 64));

                float maj0 = fmaxf(softplus_f(mx0), 0.001f);
                float maj1 = fmaxf(softplus_f(mx1), 0.001f);
                float maj2 = fmaxf(softplus_f(mx2), 0.001f);
                float mmax = fmaxf(fmaxf(maj0, maj1), maj2);

                float den0 = __expf(-maj0*span1)/(mmax+EPSF) + EPSF;
                float den1 = __expf(-maj1*span1)/(mmax+EPSF) + EPSF;
                float den2 = __expf(-maj2*span1)/(mmax+EPSF) + EPSF;
                float idm = 3.0f / (den0+den1+den2);
                float v0,v1,v2;
                env_logv(env_map, fmaf(pdx,fars1,pox), fmaf(pdy,fars1,poy),
                         fmaf(pdz,fars1,poz), v0,v1,v2);
                rgb0 += pt0 * den0*idm*__expf(v0);
                rgb1 += pt1 * den1*idm*__expf(v1);
                rgb2 += pt2 * den2*idm*__expf(v2);
            }
        }
    }

    // ---- reduction: each sub-ray duplicated x2 -> sum/256 == mean/128 ----
    float r0 = rgb0, r1 = rgb1, r2 = rgb2;
    #pragma unroll
    for (int off = 32; off > 0; off >>= 1) {
        r0 += __shfl_down(r0, off, 64);
        r1 += __shfl_down(r1, off, 64);
        r2 += __shfl_down(r2, off, 64);
    }
    int wave = tid >> 6;
    if ((tid & 63) == 0) {
        sred[wave][0] = r0; sred[wave][1] = r1; sred[wave][2] = r2;
    }
    __syncthreads();
    if (tid == 0) {
        out[ray*3+0] = (sred[0][0]+sred[1][0]+sred[2][0]+sred[3][0]) * (1.0f/256.0f);
        out[ray*3+1] = (sred[0][1]+sred[1][1]+sred[2][1]+sred[3][1]) * (1.0f/256.0f);
        out[ray*3+2] = (sred[0][2]+sred[1][2]+sred[2][2]+sred[3][2]) * (1.0f/256.0f);
    }
}

extern "C" void kernel_launch(void* const* d_in, const int* in_sizes, int n_in,
                              void* d_out, int out_size, void* d_ws, size_t ws_size,
                              hipStream_t stream) {
    const float* rays_o    = (const float*)d_in[0];
    const float* rays_d    = (const float*)d_in[1];
    const float* env_map   = (const float*)d_in[2];
    const float* Wd1       = (const float*)d_in[3];
    const float* Wd2       = (const float*)d_in[4];
    const float* Wf1       = (const float*)d_in[5];
    const float* Ws        = (const float*)d_in[6];
    const float* Wdir      = (const float*)d_in[7];
    const float* Wrho      = (const float*)d_in[8];
    const float* jitter    = (const float*)d_in[9];
    const float* u_t       = (const float*)d_in[10];
    const float* u_scatter = (const float*)d_in[11];
    const int*   channel   = (const int*)d_in[12];
    float* out = (float*)d_out;

    render_kernel<<<dim3(NRAYS), dim3(256), 0, stream>>>(
        rays_o, rays_d, env_map, Wd1, Wd2, Wf1, Ws, Wdir, Wrho,
        jitter, u_t, u_scatter, channel, out);
}